// Round 8
// baseline (2096.477 us; speedup 1.0000x reference)
//
#include <hip/hip_runtime.h>
#include <hip/hip_bf16.h>
#include <math.h>

#define DEV __device__ __forceinline__

typedef __attribute__((ext_vector_type(8))) short bf16x8;
typedef __attribute__((ext_vector_type(4))) float f32x4;
typedef unsigned short u16;

constexpr int D_ = 1024, NTOK = 16384, SEQ = 4096;

DEV u16 f2b(float f){
  union{float f;unsigned u;} v; v.f=f;
  unsigned r = (v.u + 0x7fffu + ((v.u>>16)&1u))>>16;
  return (u16)r;
}
DEV float b2f(u16 h){ union{unsigned u;float f;} v; v.u=((unsigned)h)<<16; return v.f; }

DEV float gelu_f(float x){
  float z = 0.7978845608028654f*(x + 0.044715f*x*x*x);
  float e = __expf(-2.f*z);
  float t = 2.f/(1.f+e) - 1.f;
  return 0.5f*x*(1.f+t);
}

DEV void gld16(const void* g, void* l){
  __builtin_amdgcn_global_load_lds((const __attribute__((address_space(1))) void*)g,
                                   (__attribute__((address_space(3))) void*)l, 16, 0, 0);
}

#define BAR()    __builtin_amdgcn_s_barrier()
#define SCHED0() __builtin_amdgcn_sched_barrier(0)
#define LGKM0()  asm volatile("s_waitcnt lgkmcnt(0)" ::: "memory")
#define VM8()    asm volatile("s_waitcnt vmcnt(8)" ::: "memory")
#define VM4()    asm volatile("s_waitcnt vmcnt(4)" ::: "memory")
#define VM0()    asm volatile("s_waitcnt vmcnt(0)" ::: "memory")

DEV float blockSum(float v){
  __shared__ float sb[4];
  #pragma unroll
  for(int m=32;m>=1;m>>=1) v += __shfl_xor(v, m, 64);
  int lane = threadIdx.x & 63, wv = threadIdx.x >> 6;
  __syncthreads();
  if(lane==0) sb[wv]=v;
  __syncthreads();
  float r = sb[0]+sb[1]+sb[2]+sb[3];
  __syncthreads();
  return r;
}

// ---------------- token dtype detect: int64 vs int32 ----------------
__global__ __launch_bounds__(256) void detect_k(const int* __restrict__ xr, int* __restrict__ flag){
  int tid=threadIdx.x; float cnt=0.f;
  for(int i=tid;i<8192;i+=256) if(xr[2*i+1]!=0) cnt+=1.f;
  cnt = blockSum(cnt);
  if(tid==0) *flag = (cnt < 64.f) ? 1 : 0;
}

// ---------------- embed + PE + input LN (writes X and XN=norm(X)) ----------------
__global__ __launch_bounds__(256) void embed_k(const void* __restrict__ xv, const int* __restrict__ flag,
      const float* __restrict__ emb, const float* __restrict__ w, const float* __restrict__ b,
      u16* __restrict__ out, u16* __restrict__ outn){
  int t = blockIdx.x;
  int id;
  if(*flag) id = (int)((const long long*)xv)[t];
  else      id = ((const int*)xv)[t];
  int s = t & (SEQ-1);
  int d0 = threadIdx.x*4;
  float4 e4 = *(const float4*)(emb + (size_t)id*D_ + d0);
  float vv[4] = {e4.x, e4.y, e4.z, e4.w};
  float acc = 0.f;
  #pragma unroll
  for(int i=0;i<4;i++){
    float e = fminf(fmaxf(vv[i], -100.f), 100.f);
    int d = d0+i;
    float fr = expf(-(float)(d & ~1) * (9.210340371976184f/(float)D_));
    float ang = (float)s * fr;
    e += (d&1) ? cosf(ang) : sinf(ang);
    vv[i]=e; acc+=e;
  }
  float mean = blockSum(acc)*(1.f/D_);
  float var=0.f;
  #pragma unroll
  for(int i=0;i<4;i++){ float dd=vv[i]-mean; var+=dd*dd; }
  var = blockSum(var)*(1.f/D_);
  float rs = rsqrtf(var+1e-5f);
  float y[4];
  #pragma unroll
  for(int i=0;i<4;i++) y[i] = (vv[i]-mean)*rs*w[d0+i]+b[d0+i];
  ushort4 o; o.x=f2b(y[0]); o.y=f2b(y[1]); o.z=f2b(y[2]); o.w=f2b(y[3]);
  *(ushort4*)(out + (size_t)t*D_ + d0) = o;
  float m2 = blockSum(y[0]+y[1]+y[2]+y[3])*(1.f/D_);
  float v2=0.f;
  #pragma unroll
  for(int i=0;i<4;i++){ float dd=y[i]-m2; v2+=dd*dd; }
  v2 = blockSum(v2)*(1.f/D_);
  float rs2 = rsqrtf(v2+1e-5f);
  ushort4 on; on.x=f2b((y[0]-m2)*rs2); on.y=f2b((y[1]-m2)*rs2); on.z=f2b((y[2]-m2)*rs2); on.w=f2b((y[3]-m2)*rs2);
  *(ushort4*)(outn + (size_t)t*D_ + d0) = on;
}

// ---------------- LayerNorm family ----------------
template<int MODE,int WRN>
__global__ __launch_bounds__(256) void ln_k(const u16* __restrict__ in, const u16* __restrict__ res,
      const float* __restrict__ w, const float* __restrict__ b, u16* __restrict__ out,
      u16* __restrict__ outn){
  int t = blockIdx.x; int d0 = threadIdx.x*4;
  ushort4 r4 = *(const ushort4*)(in + (size_t)t*D_ + d0);
  float vv[4] = {b2f(r4.x),b2f(r4.y),b2f(r4.z),b2f(r4.w)};
  float mean = blockSum(vv[0]+vv[1]+vv[2]+vv[3])*(1.f/D_);
  float var=0.f;
  #pragma unroll
  for(int i=0;i<4;i++){ float dd=vv[i]-mean; var+=dd*dd; }
  var = blockSum(var)*(1.f/D_);
  float rs = rsqrtf(var+1e-5f);
  float rv[4]={0,0,0,0};
  if(MODE==3){
    ushort4 q4 = *(const ushort4*)(res + (size_t)t*D_ + d0);
    rv[0]=b2f(q4.x); rv[1]=b2f(q4.y); rv[2]=b2f(q4.z); rv[3]=b2f(q4.w);
  }
  float y[4];
  #pragma unroll
  for(int i=0;i<4;i++){
    float v = (vv[i]-mean)*rs;
    v = v*w[d0+i]+b[d0+i];
    if(MODE==2) v = fminf(fmaxf(v,-100.f),100.f);
    if(MODE==3) v += rv[i];
    y[i]=v;
  }
  ushort4 o; o.x=f2b(y[0]); o.y=f2b(y[1]); o.z=f2b(y[2]); o.w=f2b(y[3]);
  *(ushort4*)(out + (size_t)t*D_ + d0) = o;
  if(WRN){
    float m2 = blockSum(y[0]+y[1]+y[2]+y[3])*(1.f/D_);
    float v2=0.f;
    #pragma unroll
    for(int i=0;i<4;i++){ float dd=y[i]-m2; v2+=dd*dd; }
    v2 = blockSum(v2)*(1.f/D_);
    float rs2 = rsqrtf(v2+1e-5f);
    ushort4 on; on.x=f2b((y[0]-m2)*rs2); on.y=f2b((y[1]-m2)*rs2); on.z=f2b((y[2]-m2)*rs2); on.w=f2b((y[3]-m2)*rs2);
    *(ushort4*)(outn + (size_t)t*D_ + d0) = on;
  }
}

__global__ __launch_bounds__(256) void ln3x_k(const u16* __restrict__ in,
    const float* __restrict__ w1,const float* __restrict__ b1,
    const float* __restrict__ w2,const float* __restrict__ b2, u16* __restrict__ out){
  int t=blockIdx.x, d0=threadIdx.x*4;
  ushort4 r4 = *(const ushort4*)(in + (size_t)t*D_ + d0);
  float vv[4]={b2f(r4.x),b2f(r4.y),b2f(r4.z),b2f(r4.w)};
  #pragma unroll
  for(int pass=0;pass<3;pass++){
    float mean = blockSum(vv[0]+vv[1]+vv[2]+vv[3])*(1.f/D_);
    float var=0.f;
    #pragma unroll
    for(int i=0;i<4;i++){ float dd=vv[i]-mean; var+=dd*dd; }
    var = blockSum(var)*(1.f/D_);
    float rs = rsqrtf(var+1e-5f);
    #pragma unroll
    for(int i=0;i<4;i++){
      float y=(vv[i]-mean)*rs;
      if(pass==0) y = y*w1[d0+i]+b1[d0+i];
      else if(pass==1) y = y*w2[d0+i]+b2[d0+i];
      vv[i]=y;
    }
  }
  ushort4 o;
  o.x=f2b(vv[0]); o.y=f2b(vv[1]); o.z=f2b(vv[2]); o.w=f2b(vv[3]);
  *(ushort4*)(out + (size_t)t*D_ + d0) = o;
}

__global__ __launch_bounds__(256) void lnrow_k(const float* __restrict__ x, const float* __restrict__ w,
      const float* __restrict__ b, float* __restrict__ out){
  int d0=threadIdx.x*4;
  float vv[4]={x[d0],x[d0+1],x[d0+2],x[d0+3]};
  float mean = blockSum(vv[0]+vv[1]+vv[2]+vv[3])*(1.f/D_);
  float var=0.f;
  #pragma unroll
  for(int i=0;i<4;i++){ float dd=vv[i]-mean; var+=dd*dd; }
  var = blockSum(var)*(1.f/D_);
  float rs = rsqrtf(var+1e-5f);
  #pragma unroll
  for(int i=0;i<4;i++) out[d0+i]=(vv[i]-mean)*rs*w[d0+i]+b[d0+i];
}

// ---------------- 64x64 transpose body macro ----------------
#define TF_BODY(W, ldW, lnw, Wt, Kd, n0, k0)                                 \
  {                                                                          \
    int ty = threadIdx.x>>6, tx = threadIdx.x&63;                            \
    _Pragma("unroll")                                                        \
    for(int p=0;p<16;p++){                                                   \
      int row = p*4+ty;                                                      \
      float sc = (lnw) ? (lnw)[(k0)+row] : 1.f;                              \
      T[row][tx] = (W)[(size_t)((k0)+row)*(ldW) + (n0)+tx]*sc;               \
    }                                                                        \
    __syncthreads();                                                         \
    _Pragma("unroll")                                                        \
    for(int p=0;p<16;p++){                                                   \
      int row = p*4+ty;                                                      \
      (Wt)[(size_t)((n0)+row)*(Kd) + (k0)+tx] = f2b(T[tx][row]);             \
    }                                                                        \
  }

__global__ __launch_bounds__(256) void tf_k(const float* __restrict__ W, int ldW,
      const float* __restrict__ lnw, u16* __restrict__ Wt, int Kd){
  __shared__ float T[64][65];
  int n0 = blockIdx.x*64, k0 = blockIdx.y*64;
  TF_BODY(W, ldW, lnw, Wt, Kd, n0, k0)
}

__global__ __launch_bounds__(256) void prep_tf_layer_k(const float* __restrict__ pw,
      const float* __restrict__ w1, const float* __restrict__ w2, const float* __restrict__ lw,
      u16* __restrict__ Wqk, u16* __restrict__ Wv, u16* __restrict__ Wo,
      u16* __restrict__ W1t, u16* __restrict__ W2t){
  __shared__ float T[64][65];
  int bid = blockIdx.x;
  const float* W; int ldW; const float* lnw; u16* Wt; int Kd, n0, k0;
  if(bid < 1024){
    int m = bid>>8, t = bid&255;
    n0 = (t&15)*64; k0 = (t>>4)*64;
    W = pw + (size_t)m*1024*1024; ldW = 1024; Kd = 1024;
    lnw = (m<3) ? lw + m*1024 : nullptr;
    Wt = (m==0)?Wqk : (m==1)?(Wqk+1024*1024) : (m==2)?Wv : Wo;
  } else if(bid < 2048){
    int t = bid-1024;
    n0 = (t&63)*64; k0 = (t>>6)*64;
    W = w1; ldW = 4096; Kd = 1024; lnw = lw+4*1024; Wt = W1t;
  } else {
    int t = bid-2048;
    n0 = (t&15)*64; k0 = (t>>4)*64;
    W = w2; ldW = 1024; Kd = 4096; lnw = nullptr; Wt = W2t;
  }
  TF_BODY(W, ldW, lnw, Wt, Kd, n0, k0)
}

__global__ __launch_bounds__(256) void prep_tf_pool_k(const float* __restrict__ pw,
      const float* __restrict__ lw, u16* __restrict__ PWkv, u16* __restrict__ PWo){
  __shared__ float T[64][65];
  int bid = blockIdx.x;
  int m = 1 + (bid>>8), t = bid&255;
  int n0 = (t&15)*64, k0 = (t>>4)*64;
  const float* W = pw + (size_t)m*1024*1024;
  const float* lnw = (m<3) ? lw + m*1024 : nullptr;
  u16* Wt = (m==1)?PWkv : (m==2)?(PWkv+1024*1024) : PWo;
  TF_BODY(W, 1024, lnw, Wt, 1024, n0, k0)
}

// ---------------- bias fold ----------------
DEV void bias_body(const float* W, int ldW, int Kd, const float* lnb, float pbv, float* out){
  int tid = threadIdx.x;
  float chk = 0.f;
  if(lnb){ for(int k=tid;k<Kd;k+=256) chk += fabsf(lnb[k]); }
  chk = blockSum(chk);
  if(chk==0.f){ if(tid==0) *out = pbv; return; }
  float s=0.f;
  for(int k=tid;k<Kd;k+=256) s += lnb[k]*W[(size_t)k*ldW];
  s = blockSum(s);
  if(tid==0) *out = pbv + s;
}

__global__ __launch_bounds__(256) void bias_k(const float* __restrict__ W, int ldW,
      const float* __restrict__ lnb, const float* __restrict__ pb, float* __restrict__ out, int Kd){
  int j = blockIdx.x;
  bias_body(W + j, ldW, Kd, lnb, pb[j], out + j);
}

__global__ __launch_bounds__(256) void prep_bias_layer_k(const float* __restrict__ pw,
      const float* __restrict__ w1, const float* __restrict__ w2,
      const float* __restrict__ lb, const float* __restrict__ pb,
      const float* __restrict__ b1in, const float* __restrict__ b2in,
      float* __restrict__ Bqk, float* __restrict__ Bv, float* __restrict__ Bo,
      float* __restrict__ B1, float* __restrict__ B2){
  int j = blockIdx.x;
  const float* W; int ldW, Kd; const float* lnb; float pbv; float* out;
  const size_t MM = 1024ull*1024;
  if(j<2048){ int m=j>>10; int col=j&1023; W=pw+m*MM+col; ldW=1024; Kd=1024; lnb=lb+m*1024; pbv=pb[m*1024+col]; out=Bqk+j; }
  else if(j<3072){ int col=j-2048; W=pw+2*MM+col; ldW=1024; Kd=1024; lnb=lb+2*1024; pbv=pb[2*1024+col]; out=Bv+col; }
  else if(j<4096){ int col=j-3072; W=pw+3*MM+col; ldW=1024; Kd=1024; lnb=nullptr; pbv=pb[3*1024+col]; out=Bo+col; }
  else if(j<8192){ int col=j-4096; W=w1+col; ldW=4096; Kd=1024; lnb=lb+4*1024; pbv=b1in[col]; out=B1+col; }
  else { int col=j-8192; W=w2+col; ldW=1024; Kd=4096; lnb=nullptr; pbv=b2in[col]; out=B2+col; }
  bias_body(W, ldW, Kd, lnb, pbv, out);
}

__global__ __launch_bounds__(256) void prep_bias_pool_k(const float* __restrict__ pw,
      const float* __restrict__ lb, const float* __restrict__ pb,
      float* __restrict__ Pbkv, float* __restrict__ Pbo){
  int j = blockIdx.x;
  const size_t MM = 1024ull*1024;
  int m = 1 + (j>>10), col = j&1023;
  const float* lnb = (m<3) ? lb + m*1024 : nullptr;
  float* out = (m==1)?(Pbkv+col) : (m==2)?(Pbkv+1024+col) : (Pbo+col);
  bias_body(pw + m*MM + col, 1024, 1024, lnb, pb[m*1024+col], out);
}

__global__ __launch_bounds__(256) void matvec_k(const float* __restrict__ xn, const float* __restrict__ W,
      int ldW, const float* __restrict__ bias, float* __restrict__ out){
  int j=blockIdx.x, tid=threadIdx.x;
  float s=0.f;
  for(int k=tid;k<1024;k+=256) s += xn[k]*W[(size_t)k*ldW + j];
  s=blockSum(s);
  if(tid==0) out[j]=s+bias[j];
}

// ---------------- GEMM: C[M,N] = A[M,K](bf16) * Bt[N,K](bf16) + bias ----------------
// 4-buffer deep pipeline: stage t+3 at iter t; end-of-iter waits retire exactly
// tile t+1 (vmcnt(8)) which was issued TWO iterations earlier -> ~2000cy latency
// tolerance. Tail drains 8->4->0. Raw s_barrier; T2 swizzle kept (conflicts=0).
template<int EPI,int OUTF,int TV>
__global__ __launch_bounds__(256) void gemm_k(const u16* __restrict__ A, const u16* __restrict__ Bt,
      const float* __restrict__ bias, const u16* __restrict__ resid, void* __restrict__ Cout,
      int M, int N, int K, int ldc){
  __shared__ u16 SH[32768];           // 4 bufs x (A 4096 + B 4096) u16 = 64 KB
  int tid = threadIdx.x, lane = tid&63, wv = tid>>6;
  int g = lane>>4, l15 = lane&15;
  int GX = gridDim.x;
  int nwg = GX*gridDim.y;
  int flat = blockIdx.y*GX + blockIdx.x;
  int q = nwg>>3, r = nwg&7, xcd = flat&7, idx = flat>>3;
  int f = (xcd<r ? xcd*(q+1) : r*(q+1)+(xcd-r)*q) + idx;
  int by = f/GX, bx = f - by*GX;
  int row0 = by*128, col0 = bx*128;
  int wr = wv>>1, wc = wv&1;
  int e0 = wv*512 + lane*8;
  f32x4 acc[4][4] = {};
  auto STAGE = [&](int buf, int t){
    u16* base = SH + buf*8192;
    int k0 = t<<5;
    #pragma unroll
    for(int c=0;c<2;c++){
      int e = c*2048 + e0;
      int row = e>>5;
      int slx = ((e>>3)&3) ^ ((row>>1)&3);   // inverse-swizzled source slot
      gld16(A  + (size_t)(row0 + row)*K + (k0 + slx*8), &base[e]);
      gld16(Bt + (size_t)(col0 + row)*K + (k0 + slx*8), &base[4096 + e]);
    }
  };
  int nt = K>>5;
  STAGE(0,0); STAGE(1,1); STAGE(2,2);
  VM8(); LGKM0(); BAR(); SCHED0();
  #pragma unroll 4
  for(int t=0;t<nt;t++){
    int b = t&3;
    if(t+3<nt) STAGE((t+3)&3, t+3);
    bf16x8 a[4], bb[4];
    #pragma unroll
    for(int m=0;m<4;m++){
      int ra = wr*64+m*16+l15;
      a[m] = *(const bf16x8*)&SH[b*8192 + ra*32 + ((g ^ ((ra>>1)&3))<<3)];
    }
    #pragma unroll
    for(int n=0;n<4;n++){
      int rb = wc*64+n*16+l15;
      bb[n] = *(const bf16x8*)&SH[b*8192 + 4096 + rb*32 + ((g ^ ((rb>>1)&3))<<3)];
    }
    #pragma unroll
    for(int m=0;m<4;m++)
      #pragma unroll
      for(int n=0;n<4;n++)
        acc[m][n] = __builtin_amdgcn_mfma_f32_16x16x32_bf16(a[m], bb[n], acc[m][n], 0,0,0);
    if(t+1<nt){
      if(t+3<nt)      { VM8(); }
      else if(t+2<nt) { VM4(); }
      else            { VM0(); }
      LGKM0(); BAR(); SCHED0();
    }
  }
  if(TV){
    __syncthreads();
    u16* Tb = SH;
    #pragma unroll
    for(int m=0;m<4;m++){
      #pragma unroll
      for(int n=0;n<4;n++){
        int c = wc*64 + n*16 + l15;
        float bs = bias[col0 + c];
        #pragma unroll
        for(int r2=0;r2<4;r2++){
          int Rl = wr*64 + m*16 + g*4 + r2;
          Tb[c*128 + (Rl ^ ((c&7)<<4))] = f2b(acc[m][n][r2]+bs);
        }
      }
    }
    __syncthreads();
    for(int p=tid*4; p<16384; p+=1024){
      int c = p>>7, rr = p&127;
      int rs = rr ^ ((c&7)<<4);
      ushort4 v4;
      v4.x = Tb[c*128+rs]; v4.y = Tb[c*128+rs+1]; v4.z = Tb[c*128+rs+2]; v4.w = Tb[c*128+rs+3];
      *(ushort4*)((u16*)Cout + (size_t)(col0+c)*M + row0 + rr) = v4;
    }
  } else {
    #pragma unroll
    for(int m=0;m<4;m++){
      #pragma unroll
      for(int n=0;n<4;n++){
        int Cc = col0 + wc*64 + n*16 + l15;
        float bs = bias[Cc];
        #pragma unroll
        for(int r2=0;r2<4;r2++){
          int R = row0 + wr*64 + m*16 + g*4 + r2;
          float v = acc[m][n][r2] + bs;
          if(EPI==1) v = gelu_f(v);
          if(EPI==2) v += b2f(resid[(size_t)R*ldc + Cc]);
          if(OUTF) ((float*)Cout)[(size_t)R*ldc + Cc] = v;
          else     ((u16*)Cout)[(size_t)R*ldc + Cc] = f2b(v);
        }
      }
    }
  }
}

// ---------------- local block attention (S=128, dk=64), MFMA, T2-swizzled ----------------
__global__ __launch_bounds__(256) void attnl_k(const u16* __restrict__ QK, const u16* __restrict__ VT,
      u16* __restrict__ AT){
  __shared__ u16 SP[16384];
  __shared__ u16 Vt[8192];
  __shared__ float rmax[256], rsum[256];
  int tid=threadIdx.x, lane=tid&63, wv=tid>>6, g=lane>>4, l15=lane&15;
  int lb = blockIdx.x>>4, h = blockIdx.x&15;
  int wr=wv>>1, wc=wv&1;
  #pragma unroll
  for(int c=0;c<4;c++){
    int chunk = c*2048 + wv*512;
    int e = chunk + lane*8;
    int rq = e>>6;
    int sq = ((e>>3)&7) ^ (rq&7);
    int rv = e>>7;
    int sv = ((e>>3)&15) ^ (rv&15);
    gld16(QK + (size_t)(lb*128 + rq)*2048 + h*64 + sq*8,        &SP[chunk]);
    gld16(QK + (size_t)(lb*128 + rq)*2048 + 1024 + h*64 + sq*8, &SP[8192+chunk]);
    gld16(VT + (size_t)(h*64 + rv)*16384 + lb*128 + sv*8,       &Vt[chunk]);
  }
  __syncthreads();
  f32x4 s[4][4] = {};
  #pragma unroll
  for(int ks=0;ks<2;ks++){
    bf16x8 a[4], b[4];
    #pragma unroll
    for(int m=0;m<4;m++){
      int ra = wr*64+m*16+l15;
      a[m] = *(const bf16x8*)&SP[ra*64 + (((ks*4+g) ^ (ra&7))<<3)];
    }
    #pragma unroll
    for(int n=0;n<4;n++){
      int rb = wc*64+n*16+l15;
      b[n] = *(const bf16x8*)&SP[8192 + rb*64 + (((ks*4+g) ^ (rb&7))<<3)];
    }
    #pragma unroll
    for(int m=0;m<4;m++)
      #pragma unroll
      for(int n=0;n<4;n++)
        s[m][n] = __builtin_amdgcn_mfma_f32_16x16x32_bf16(a[m], b[n], s[m][n], 0,0,0);
  }
  #pragma unroll
  for(int m=0;m<4;m++)
    #pragma unroll
    for(int n=0;n<4;n++) s[m][n] *= 0.125f;
  #pragma unroll
  for(int m=0;m<4;m++)
    #pragma unroll
    for(int r=0;r<4;r++){
      float mx = fmaxf(fmaxf(s[m][0][r],s[m][1][r]),fmaxf(s[m][2][r],s[m][3][r]));
      #pragma unroll
      for(int msk=1;msk<16;msk<<=1) mx = fmaxf(mx, __shfl_xor(mx,msk,64));
      if(l15==0) rmax[(wr*64+m*16+g*4+r)*2+wc]=mx;
    }
  __syncthreads();
  #pragma unroll
  for(int m=0;m<4;m++)
    #pragma unroll
    for(int r=0;r<4;r++){
      int row = wr*64+m*16+g*4+r;
      float M2 = fmaxf(rmax[row*2], rmax[row*2+1]);
      float sm=0.f;
      #pragma unroll
      for(int n=0;n<4;n++){ float e = expf(s[m][n][r]-M2); s[m][n][r]=e; sm+=e; }
      #pragma unroll
      for(int msk=1;msk<16;msk<<=1) sm += __shfl_xor(sm,msk,64);
      if(l15==0) rsum[row*2+wc]=sm;
    }
  __syncthreads();
  #pragma unroll
  for(int m=0;m<4;m++)
    #pragma unroll
    for(int r=0;r<4;r++){
      int row = wr*64+m*16+g*4+r;
      float den = rsum[row*2]+rsum[row*2+1]+1e-9f;
      #pragma unroll
      for(int n=0;n<4;n++){
        float a = s[m][n][r]/den;
        a = fminf(fmaxf(a,1e-9f),1.f);
        int col = wc*64+n*16+l15;
        SP[row*128 + ((((col>>3) ^ (row&15))<<3) | (col&7))] = f2b(a);
      }
    }
  __syncthreads();
  f32x4 o[4][2] = {};
  #pragma unroll
  for(int ks=0;ks<4;ks++){
    bf16x8 a[4], b[2];
    #pragma unroll
    for(int m=0;m<4;m++){
      int ra = wr*64+m*16+l15;
      a[m] = *(const bf16x8*)&SP[ra*128 + (((ks*4+g) ^ (ra&15))<<3)];
    }
    #pragma unroll
    for(int n=0;n<2;n++){
      int rv = wc*32+n*16+l15;
      b[n] = *(const bf16x8*)&Vt[rv*128 + (((ks*4+g) ^ (rv&15))<<3)];
    }
    #pragma unroll
    for(int m=0;m<4;m++)
      #pragma unroll
      for(int n=0;n<2;n++)
        o[m][n] = __builtin_amdgcn_mfma_f32_16x16x32_bf16(a[m], b[n], o[m][n], 0,0,0);
  }
  #pragma unroll
  for(int m=0;m<4;m++)
    #pragma unroll
    for(int n=0;n<2;n++)
      #pragma unroll
      for(int r=0;r<4;r++)
        AT[(size_t)(lb*128 + wr*64+m*16+g*4+r)*1024 + h*64 + wc*32+n*16+l15] = f2b(o[m][n][r]);
}

// ---------------- pooling attention ----------------
__global__ __launch_bounds__(256) void poolattn_k(const float* __restrict__ qp, const u16* __restrict__ KV,
      u16* __restrict__ g0){
  int lb = blockIdx.x, tid = threadIdx.x;
  __shared__ float sc[16*128];
  for(int p=tid;p<2048;p+=256){
    int h=p>>7, j=p&127;
    const u16* krow = KV + (size_t)(lb*128+j)*2048 + h*64;
    float s=0.f;
    for(int d=0;d<64;d++) s += qp[h*64+d]*b2f(krow[d]);
    sc[h*128+j] = s*0.125f;
  }
  __syncthreads();
  if(tid<16){
    float* r=&sc[tid*128];
    float mx=r[0];
    for(int j=1;j<128;j++) mx=fmaxf(mx,r[j]);
    float sm=0.f;
    for(int j=0;j<128;j++){ float e=expf(r[j]-mx); r[j]=e; sm+=e; }
    sm+=1e-9f;
    for(int j=0;j<128;j++) r[j]=fminf(fmaxf(r[j]/sm,1e-9f),1.f);
  }
  __syncthreads();
  for(int c=tid;c<1024;c+=256){
    int h=c>>6;
    float acc=0.f;
    for(int j=0;j<128;j++) acc += sc[h*128+j]*b2f(KV[(size_t)(lb*128+j)*2048 + 1024 + c]);
    g0[(size_t)lb*1024 + c] = f2b(acc);
  }
}

// ---------------- global attention ----------------
__global__ __launch_bounds__(256) void attng_k(const u16* __restrict__ QKV, u16* __restrict__ OUT){
  int bb = blockIdx.x>>4, h = blockIdx.x&15;
  __shared__ float sc[32*32];
  int tid=threadIdx.x;
  for(int p=tid;p<1024;p+=256){
    int i=p>>5, j=p&31;
    const u16* q = QKV + (size_t)(bb*32+i)*3072 + h*64;
    const u16* k = QKV + (size_t)(bb*32+j)*3072 + 1024 + h*64;
    float s=0.f;
    for(int d=0;d<64;d++) s += b2f(q[d])*b2f(k[d]);
    sc[p] = s*0.125f;
  }
  __syncthreads();
  if(tid<32){
    float* r=&sc[tid*32];
    float mx=r[0];
    for(int j=1;j<32;j++) mx=fmaxf(mx,r[j]);
    float sm=0.f;
    for(int j=0;j<32;j++){ float e=expf(r[j]-mx); r[j]=e; sm+=e; }
    sm+=1e-9f;
    for(int j=0;j<32;j++) r[j]=fminf(fmaxf(r[j]/sm,1e-9f),1.f);
  }
  __syncthreads();
  for(int p=tid;p<2048;p+=256){
    int i=p>>6, d=p&63;
    float acc=0.f;
    for(int j=0;j<32;j++) acc += sc[i*32+j]*b2f(QKV[(size_t)(bb*32+j)*3072 + 2048 + h*64 + d]);
    OUT[(size_t)(bb*32+i)*1024 + h*64 + d] = f2b(acc);
  }
}

extern "C" void kernel_launch(void* const* d_in, const int* in_sizes, int n_in,
                              void* d_out, int out_size, void* d_ws, size_t ws_size,
                              hipStream_t stream) {
  (void)in_sizes; (void)n_in; (void)out_size;
  const void*  x       = d_in[0];
  const float* emb     = (const float*)d_in[1];
  const float* in_ln_w = (const float*)d_in[2];
  const float* in_ln_b = (const float*)d_in[3];
  const float* loc_ln_w= (const float*)d_in[4];
  const float* loc_ln_b= (const float*)d_in[5];
  const float* loc_pw  = (const float*)d_in[6];
  const float* loc_pb  = (const float*)d_in[7];
  const float* loc_w1  = (const float*)d_in[8];
  const float* loc_b1  = (const float*)d_in[9];
  const float* loc_w2  = (const float*)d_in[10];
  const float* loc_b2  = (const float*)d_in[11];
  const float* locn_w  = (const float*)d_in[12];
  const float* locn_b  = (const float*)d_in[13];
  const float* pool_q  = (const float*)d_in[14];
  const float* pool_n_w= (const float*)d_in[15];
  const float* pool_n_b= (const float*)d_in[16];
  const float* pool_ln_w=(const float*)d_in[17];
  const float* pool_ln_b=(const float*)d_in[18];
  const float* pool_pw = (const float*)d_in[19];
  const float* pool_pb = (const float*)d_in[20];
  const float* glob_ln_w=(const float*)d_in[21];
  const float* glob_ln_b=(const float*)d_in[22];
  const float* glob_pw = (const float*)d_in[23];
  const float* glob_pb = (const float*)d_in[24];
  const float* glob_w1 = (const float*)d_in[25];
  const float* glob_b1 = (const float*)d_in[26];
  const float* glob_w2 = (const float*)d_in[27];
  const float* glob_b2 = (const float*)d_in[28];
  const float* out_ln_w= (const float*)d_in[29];
  const float* out_ln_b= (const float*)d_in[30];
  const float* out_w   = (const float*)d_in[31];
  const float* out_b   = (const float*)d_in[32];

  char* wsb = (char*)d_ws;
  size_t off = 0;
  auto AL = [&](size_t n)->char*{ size_t o=(off+255)&~(size_t)255; off=o+n; return wsb+o; };

  int*  flag = (int*)AL(256);
  u16*  WA   = (u16*)AL(12ull*1024*1024*2);
  float* BA  = (float*)AL(12*1024*4);
  float* qn  = (float*)AL(1024*4);
  float* qp  = (float*)AL(1024*4);
  float* Hb  = (float*)AL(32000*4);
  u16*  R    = (u16*)AL(64ull*1024*1024*2);
  u16*  X    = (u16*)AL((size_t)NTOK*1024*2);
  u16*  XN   = (u16*)AL((size_t)NTOK*1024*2);
  u16*  G    = (u16*)AL(128ull*1024*2);
  u16*  GN   = (u16*)AL(128ull*1024*2);
  u16*  GQKV = (u16*)AL(128ull*3072*2);
  u16*  GAT  = (u16*)AL(128ull*1024*2);
  u16*  GO   = (u16*)AL(128ull*1024*2);
  u16*  GFH  = (u16*)AL(128ull*4096*2);
  u16*  g0   = (u16*)AL(128ull*1024*2);
  if(off > ws_size) return;

  u16 *LWqk = WA, *LWv = WA+2097152, *LWo = WA+3145728, *LW1 = WA+4194304, *LW2 = WA+8388608;
  float *Lbqk = BA, *Lbv = BA+2048, *Lbo = BA+3072, *Lb1 = BA+4096, *Lb2 = BA+8192;
  u16 *GWqkv = WA, *GWo = WA+3145728, *GW1 = WA+4194304, *GW2 = WA+8388608;
  float *Gbqkv = BA, *Gbo = BA+3072, *Gb1 = BA+4096, *Gb2 = BA+8192;
  u16 *PWkv = WA, *PWo = WA+2097152;
  float *Pbkv = BA, *Pbo = BA+2048;
  u16 *QKb = R, *VTb = R+33554432, *ATb = R+50331648;
  u16 *FH  = R;
  u16 *KVb = R;
  u16 *HW  = R;
  u16 *Ob  = XN;

  const size_t MM = 1024ull*1024;

  detect_k<<<1,256,0,stream>>>((const int*)x, flag);
  embed_k<<<NTOK,256,0,stream>>>(x, flag, emb, in_ln_w, in_ln_b, X, XN);

  for(int l=0;l<2;l++){
    const float* pw = loc_pw + (size_t)l*4*MM;
    const float* lw = loc_ln_w + (size_t)l*6*1024;
    const float* lb = loc_ln_b + (size_t)l*6*1024;
    const float* pb = loc_pb + (size_t)l*4*1024;
    const float* w1 = loc_w1 + (size_t)l*1024*4096;
    const float* w2 = loc_w2 + (size_t)l*4096*1024;
    prep_tf_layer_k<<<3072,256,0,stream>>>(pw, w1, w2, lw, LWqk, LWv, LWo, LW1, LW2);
    prep_bias_layer_k<<<9216,256,0,stream>>>(pw, w1, w2, lb, pb,
        loc_b1+(size_t)l*4096, loc_b2+(size_t)l*1024, Lbqk, Lbv, Lbo, Lb1, Lb2);

    gemm_k<0,0,0><<<dim3(16,128),256,0,stream>>>(XN, LWqk, Lbqk, nullptr, QKb, NTOK, 2048, 1024, 2048);
    gemm_k<0,0,1><<<dim3(8,128),256,0,stream>>>(XN, LWv, Lbv, nullptr, VTb, NTOK, 1024, 1024, 0);
    attnl_k<<<128*16,256,0,stream>>>(QKb, VTb, ATb);
    gemm_k<0,0,0><<<dim3(8,128),256,0,stream>>>(ATb, LWo, Lbo, nullptr, Ob, NTOK, 1024, 1024, 1024);
    ln_k<3,1><<<NTOK,256,0,stream>>>(Ob, X, lw+3*1024, lb+3*1024, X, XN);
    gemm_k<1,0,0><<<dim3(32,128),256,0,stream>>>(XN, LW1, Lb1, nullptr, FH, NTOK, 4096, 1024, 4096);
    gemm_k<2,0,0><<<dim3(8,128),256,0,stream>>>(FH, LW2, Lb2, X, Ob, NTOK, 1024, 4096, 1024);
    ln_k<2,1><<<NTOK,256,0,stream>>>(Ob, nullptr, lw+5*1024, lb+5*1024, X, XN);
  }

  prep_tf_pool_k<<<768,256,0,stream>>>(pool_pw, pool_ln_w, PWkv, PWo);
  prep_bias_pool_k<<<3072,256,0,stream>>>(pool_pw, pool_ln_b, pool_pb, Pbkv, Pbo);
  lnrow_k<<<1,256,0,stream>>>(pool_q, pool_ln_w, pool_ln_b, qn);
  matvec_k<<<1024,256,0,stream>>>(qn, pool_pw, 1024, pool_pb, qp);
  ln3x_k<<<NTOK,256,0,stream>>>(X, locn_w, locn_b, pool_n_w, pool_n_b, XN);
  gemm_k<0,0,0><<<dim3(16,128),256,0,stream>>>(XN, PWkv, Pbkv, nullptr, KVb, NTOK, 2048, 1024, 2048);
  poolattn_k<<<128,256,0,stream>>>(qp, KVb, g0);
  gemm_k<0,0,0><<<dim3(8,1),256,0,stream>>>(g0, PWo, Pbo, nullptr, GO, 128, 1024, 1024, 1024);
  ln_k<1,1><<<128,256,0,stream>>>(GO, nullptr, pool_ln_w+3*1024, pool_ln_b+3*1024, G, GN);

  for(int l=0;l<2;l++){
    const float* pw = glob_pw + (size_t)l*4*MM;
    const float* lw = glob_ln_w + (size_t)l*6*1024;
    const float* lb = glob_ln_b + (size_t)l*6*1024;
    const float* pb = glob_pb + (size_t)l*4*1024;
    const float* w1 = glob_w1 + (size_t)l*1024*4096;
    const float* w2 = glob_w2 + (size_t)l*4096*1024;
    prep_tf_layer_k<<<3072,256,0,stream>>>(pw, w1, w2, lw, GWqkv, GWqkv+2097152, GWo, GW1, GW2);
    prep_bias_layer_k<<<9216,256,0,stream>>>(pw, w1, w2, lb, pb,
        glob_b1+(size_t)l*4096, glob_b2+(size_t)l*1024, Gbqkv, Gbqkv+2048, Gbo, Gb1, Gb2);

    gemm_k<0,0,0><<<dim3(24,1),256,0,stream>>>(GN, GWqkv, Gbqkv, nullptr, GQKV, 128, 3072, 1024, 3072);
    attng_k<<<64,256,0,stream>>>(GQKV, GAT);
    gemm_k<0,0,0><<<dim3(8,1),256,0,stream>>>(GAT, GWo, Gbo, nullptr, GO, 128, 1024, 1024, 1024);
    ln_k<3,1><<<128,256,0,stream>>>(GO, G, lw+3*1024, lb+3*1024, G, GN);
    gemm_k<1,0,0><<<dim3(32,1),256,0,stream>>>(GN, GW1, Gb1, nullptr, GFH, 128, 4096, 1024, 4096);
    gemm_k<2,0,0><<<dim3(8,1),256,0,stream>>>(GFH, GW2, Gb2, G, GO, 128, 1024, 4096, 1024);
    ln_k<2,1><<<128,256,0,stream>>>(GO, nullptr, lw+5*1024, lb+5*1024, G, GN);
  }

  tf_k<<<dim3(500,16),256,0,stream>>>(out_w, 32000, out_ln_w, HW, 1024);
  bias_k<<<32000,256,0,stream>>>(out_w, 32000, out_ln_b, out_b, Hb, 1024);
  gemm_k<0,1,0><<<dim3(250,1),256,0,stream>>>(GN, HW, Hb, nullptr, d_out, 128, 32000, 1024, 32000);
}

// Round 9
// 1947.955 us; speedup vs baseline: 1.0762x; 1.0762x over previous
//
#include <hip/hip_runtime.h>
#include <hip/hip_bf16.h>
#include <math.h>

#define DEV __device__ __forceinline__

typedef __attribute__((ext_vector_type(8))) short bf16x8;
typedef __attribute__((ext_vector_type(4))) float f32x4;
typedef unsigned short u16;

constexpr int D_ = 1024, NTOK = 16384, SEQ = 4096;

DEV u16 f2b(float f){
  union{float f;unsigned u;} v; v.f=f;
  unsigned r = (v.u + 0x7fffu + ((v.u>>16)&1u))>>16;
  return (u16)r;
}
DEV float b2f(u16 h){ union{unsigned u;float f;} v; v.u=((unsigned)h)<<16; return v.f; }

DEV float gelu_f(float x){
  float z = 0.7978845608028654f*(x + 0.044715f*x*x*x);
  float e = __expf(-2.f*z);
  float t = 2.f/(1.f+e) - 1.f;
  return 0.5f*x*(1.f+t);
}

DEV void gld16(const void* g, void* l){
  __builtin_amdgcn_global_load_lds((const __attribute__((address_space(1))) void*)g,
                                   (__attribute__((address_space(3))) void*)l, 16, 0, 0);
}

#define BAR()    __builtin_amdgcn_s_barrier()
#define SCHED0() __builtin_amdgcn_sched_barrier(0)
#define LGKM0()  asm volatile("s_waitcnt lgkmcnt(0)" ::: "memory")
#define VM0()    asm volatile("s_waitcnt vmcnt(0)" ::: "memory")

DEV float blockSum(float v){
  __shared__ float sb[4];
  #pragma unroll
  for(int m=32;m>=1;m>>=1) v += __shfl_xor(v, m, 64);
  int lane = threadIdx.x & 63, wv = threadIdx.x >> 6;
  __syncthreads();
  if(lane==0) sb[wv]=v;
  __syncthreads();
  float r = sb[0]+sb[1]+sb[2]+sb[3];
  __syncthreads();
  return r;
}

// ---------------- token dtype detect: int64 vs int32 ----------------
__global__ __launch_bounds__(256) void detect_k(const int* __restrict__ xr, int* __restrict__ flag){
  int tid=threadIdx.x; float cnt=0.f;
  for(int i=tid;i<8192;i+=256) if(xr[2*i+1]!=0) cnt+=1.f;
  cnt = blockSum(cnt);
  if(tid==0) *flag = (cnt < 64.f) ? 1 : 0;
}

// ---------------- embed + PE + input LN (writes X and XN=norm(X)) ----------------
__global__ __launch_bounds__(256) void embed_k(const void* __restrict__ xv, const int* __restrict__ flag,
      const float* __restrict__ emb, const float* __restrict__ w, const float* __restrict__ b,
      u16* __restrict__ out, u16* __restrict__ outn){
  int t = blockIdx.x;
  int id;
  if(*flag) id = (int)((const long long*)xv)[t];
  else      id = ((const int*)xv)[t];
  int s = t & (SEQ-1);
  int d0 = threadIdx.x*4;
  float4 e4 = *(const float4*)(emb + (size_t)id*D_ + d0);
  float vv[4] = {e4.x, e4.y, e4.z, e4.w};
  float acc = 0.f;
  #pragma unroll
  for(int i=0;i<4;i++){
    float e = fminf(fmaxf(vv[i], -100.f), 100.f);
    int d = d0+i;
    float fr = expf(-(float)(d & ~1) * (9.210340371976184f/(float)D_));
    float ang = (float)s * fr;
    e += (d&1) ? cosf(ang) : sinf(ang);
    vv[i]=e; acc+=e;
  }
  float mean = blockSum(acc)*(1.f/D_);
  float var=0.f;
  #pragma unroll
  for(int i=0;i<4;i++){ float dd=vv[i]-mean; var+=dd*dd; }
  var = blockSum(var)*(1.f/D_);
  float rs = rsqrtf(var+1e-5f);
  float y[4];
  #pragma unroll
  for(int i=0;i<4;i++) y[i] = (vv[i]-mean)*rs*w[d0+i]+b[d0+i];
  ushort4 o; o.x=f2b(y[0]); o.y=f2b(y[1]); o.z=f2b(y[2]); o.w=f2b(y[3]);
  *(ushort4*)(out + (size_t)t*D_ + d0) = o;
  float m2 = blockSum(y[0]+y[1]+y[2]+y[3])*(1.f/D_);
  float v2=0.f;
  #pragma unroll
  for(int i=0;i<4;i++){ float dd=y[i]-m2; v2+=dd*dd; }
  v2 = blockSum(v2)*(1.f/D_);
  float rs2 = rsqrtf(v2+1e-5f);
  ushort4 on; on.x=f2b((y[0]-m2)*rs2); on.y=f2b((y[1]-m2)*rs2); on.z=f2b((y[2]-m2)*rs2); on.w=f2b((y[3]-m2)*rs2);
  *(ushort4*)(outn + (size_t)t*D_ + d0) = on;
}

// ---------------- LayerNorm family ----------------
template<int MODE,int WRN>
__global__ __launch_bounds__(256) void ln_k(const u16* __restrict__ in, const u16* __restrict__ res,
      const float* __restrict__ w, const float* __restrict__ b, u16* __restrict__ out,
      u16* __restrict__ outn){
  int t = blockIdx.x; int d0 = threadIdx.x*4;
  ushort4 r4 = *(const ushort4*)(in + (size_t)t*D_ + d0);
  float vv[4] = {b2f(r4.x),b2f(r4.y),b2f(r4.z),b2f(r4.w)};
  float mean = blockSum(vv[0]+vv[1]+vv[2]+vv[3])*(1.f/D_);
  float var=0.f;
  #pragma unroll
  for(int i=0;i<4;i++){ float dd=vv[i]-mean; var+=dd*dd; }
  var = blockSum(var)*(1.f/D_);
  float rs = rsqrtf(var+1e-5f);
  float rv[4]={0,0,0,0};
  if(MODE==3){
    ushort4 q4 = *(const ushort4*)(res + (size_t)t*D_ + d0);
    rv[0]=b2f(q4.x); rv[1]=b2f(q4.y); rv[2]=b2f(q4.z); rv[3]=b2f(q4.w);
  }
  float y[4];
  #pragma unroll
  for(int i=0;i<4;i++){
    float v = (vv[i]-mean)*rs;
    v = v*w[d0+i]+b[d0+i];
    if(MODE==2) v = fminf(fmaxf(v,-100.f),100.f);
    if(MODE==3) v += rv[i];
    y[i]=v;
  }
  ushort4 o; o.x=f2b(y[0]); o.y=f2b(y[1]); o.z=f2b(y[2]); o.w=f2b(y[3]);
  *(ushort4*)(out + (size_t)t*D_ + d0) = o;
  if(WRN){
    float m2 = blockSum(y[0]+y[1]+y[2]+y[3])*(1.f/D_);
    float v2=0.f;
    #pragma unroll
    for(int i=0;i<4;i++){ float dd=y[i]-m2; v2+=dd*dd; }
    v2 = blockSum(v2)*(1.f/D_);
    float rs2 = rsqrtf(v2+1e-5f);
    ushort4 on; on.x=f2b((y[0]-m2)*rs2); on.y=f2b((y[1]-m2)*rs2); on.z=f2b((y[2]-m2)*rs2); on.w=f2b((y[3]-m2)*rs2);
    *(ushort4*)(outn + (size_t)t*D_ + d0) = on;
  }
}

__global__ __launch_bounds__(256) void ln3x_k(const u16* __restrict__ in,
    const float* __restrict__ w1,const float* __restrict__ b1,
    const float* __restrict__ w2,const float* __restrict__ b2, u16* __restrict__ out){
  int t=blockIdx.x, d0=threadIdx.x*4;
  ushort4 r4 = *(const ushort4*)(in + (size_t)t*D_ + d0);
  float vv[4]={b2f(r4.x),b2f(r4.y),b2f(r4.z),b2f(r4.w)};
  #pragma unroll
  for(int pass=0;pass<3;pass++){
    float mean = blockSum(vv[0]+vv[1]+vv[2]+vv[3])*(1.f/D_);
    float var=0.f;
    #pragma unroll
    for(int i=0;i<4;i++){ float dd=vv[i]-mean; var+=dd*dd; }
    var = blockSum(var)*(1.f/D_);
    float rs = rsqrtf(var+1e-5f);
    #pragma unroll
    for(int i=0;i<4;i++){
      float y=(vv[i]-mean)*rs;
      if(pass==0) y = y*w1[d0+i]+b1[d0+i];
      else if(pass==1) y = y*w2[d0+i]+b2[d0+i];
      vv[i]=y;
    }
  }
  ushort4 o;
  o.x=f2b(vv[0]); o.y=f2b(vv[1]); o.z=f2b(vv[2]); o.w=f2b(vv[3]);
  *(ushort4*)(out + (size_t)t*D_ + d0) = o;
}

__global__ __launch_bounds__(256) void lnrow_k(const float* __restrict__ x, const float* __restrict__ w,
      const float* __restrict__ b, float* __restrict__ out){
  int d0=threadIdx.x*4;
  float vv[4]={x[d0],x[d0+1],x[d0+2],x[d0+3]};
  float mean = blockSum(vv[0]+vv[1]+vv[2]+vv[3])*(1.f/D_);
  float var=0.f;
  #pragma unroll
  for(int i=0;i<4;i++){ float dd=vv[i]-mean; var+=dd*dd; }
  var = blockSum(var)*(1.f/D_);
  float rs = rsqrtf(var+1e-5f);
  #pragma unroll
  for(int i=0;i<4;i++) out[d0+i]=(vv[i]-mean)*rs*w[d0+i]+b[d0+i];
}

// ---------------- 64x64 transpose body macro ----------------
#define TF_BODY(W, ldW, lnw, Wt, Kd, n0, k0)                                 \
  {                                                                          \
    int ty = threadIdx.x>>6, tx = threadIdx.x&63;                            \
    _Pragma("unroll")                                                        \
    for(int p=0;p<16;p++){                                                   \
      int row = p*4+ty;                                                      \
      float sc = (lnw) ? (lnw)[(k0)+row] : 1.f;                              \
      T[row][tx] = (W)[(size_t)((k0)+row)*(ldW) + (n0)+tx]*sc;               \
    }                                                                        \
    __syncthreads();                                                         \
    _Pragma("unroll")                                                        \
    for(int p=0;p<16;p++){                                                   \
      int row = p*4+ty;                                                      \
      (Wt)[(size_t)((n0)+row)*(Kd) + (k0)+tx] = f2b(T[tx][row]);             \
    }                                                                        \
  }

__global__ __launch_bounds__(256) void tf_k(const float* __restrict__ W, int ldW,
      const float* __restrict__ lnw, u16* __restrict__ Wt, int Kd){
  __shared__ float T[64][65];
  int n0 = blockIdx.x*64, k0 = blockIdx.y*64;
  TF_BODY(W, ldW, lnw, Wt, Kd, n0, k0)
}

__global__ __launch_bounds__(256) void prep_tf_layer_k(const float* __restrict__ pw,
      const float* __restrict__ w1, const float* __restrict__ w2, const float* __restrict__ lw,
      u16* __restrict__ Wqk, u16* __restrict__ Wv, u16* __restrict__ Wo,
      u16* __restrict__ W1t, u16* __restrict__ W2t){
  __shared__ float T[64][65];
  int bid = blockIdx.x;
  const float* W; int ldW; const float* lnw; u16* Wt; int Kd, n0, k0;
  if(bid < 1024){
    int m = bid>>8, t = bid&255;
    n0 = (t&15)*64; k0 = (t>>4)*64;
    W = pw + (size_t)m*1024*1024; ldW = 1024; Kd = 1024;
    lnw = (m<3) ? lw + m*1024 : nullptr;
    Wt = (m==0)?Wqk : (m==1)?(Wqk+1024*1024) : (m==2)?Wv : Wo;
  } else if(bid < 2048){
    int t = bid-1024;
    n0 = (t&63)*64; k0 = (t>>6)*64;
    W = w1; ldW = 4096; Kd = 1024; lnw = lw+4*1024; Wt = W1t;
  } else {
    int t = bid-2048;
    n0 = (t&15)*64; k0 = (t>>4)*64;
    W = w2; ldW = 1024; Kd = 4096; lnw = nullptr; Wt = W2t;
  }
  TF_BODY(W, ldW, lnw, Wt, Kd, n0, k0)
}

__global__ __launch_bounds__(256) void prep_tf_pool_k(const float* __restrict__ pw,
      const float* __restrict__ lw, u16* __restrict__ PWkv, u16* __restrict__ PWo){
  __shared__ float T[64][65];
  int bid = blockIdx.x;
  int m = 1 + (bid>>8), t = bid&255;
  int n0 = (t&15)*64, k0 = (t>>4)*64;
  const float* W = pw + (size_t)m*1024*1024;
  const float* lnw = (m<3) ? lw + m*1024 : nullptr;
  u16* Wt = (m==1)?PWkv : (m==2)?(PWkv+1024*1024) : PWo;
  TF_BODY(W, 1024, lnw, Wt, 1024, n0, k0)
}

// ---------------- bias fold ----------------
DEV void bias_body(const float* W, int ldW, int Kd, const float* lnb, float pbv, float* out){
  int tid = threadIdx.x;
  float chk = 0.f;
  if(lnb){ for(int k=tid;k<Kd;k+=256) chk += fabsf(lnb[k]); }
  chk = blockSum(chk);
  if(chk==0.f){ if(tid==0) *out = pbv; return; }
  float s=0.f;
  for(int k=tid;k<Kd;k+=256) s += lnb[k]*W[(size_t)k*ldW];
  s = blockSum(s);
  if(tid==0) *out = pbv + s;
}

__global__ __launch_bounds__(256) void bias_k(const float* __restrict__ W, int ldW,
      const float* __restrict__ lnb, const float* __restrict__ pb, float* __restrict__ out, int Kd){
  int j = blockIdx.x;
  bias_body(W + j, ldW, Kd, lnb, pb[j], out + j);
}

__global__ __launch_bounds__(256) void prep_bias_layer_k(const float* __restrict__ pw,
      const float* __restrict__ w1, const float* __restrict__ w2,
      const float* __restrict__ lb, const float* __restrict__ pb,
      const float* __restrict__ b1in, const float* __restrict__ b2in,
      float* __restrict__ Bqk, float* __restrict__ Bv, float* __restrict__ Bo,
      float* __restrict__ B1, float* __restrict__ B2){
  int j = blockIdx.x;
  const float* W; int ldW, Kd; const float* lnb; float pbv; float* out;
  const size_t MM = 1024ull*1024;
  if(j<2048){ int m=j>>10; int col=j&1023; W=pw+m*MM+col; ldW=1024; Kd=1024; lnb=lb+m*1024; pbv=pb[m*1024+col]; out=Bqk+j; }
  else if(j<3072){ int col=j-2048; W=pw+2*MM+col; ldW=1024; Kd=1024; lnb=lb+2*1024; pbv=pb[2*1024+col]; out=Bv+col; }
  else if(j<4096){ int col=j-3072; W=pw+3*MM+col; ldW=1024; Kd=1024; lnb=nullptr; pbv=pb[3*1024+col]; out=Bo+col; }
  else if(j<8192){ int col=j-4096; W=w1+col; ldW=4096; Kd=1024; lnb=lb+4*1024; pbv=b1in[col]; out=B1+col; }
  else { int col=j-8192; W=w2+col; ldW=1024; Kd=4096; lnb=nullptr; pbv=b2in[col]; out=B2+col; }
  bias_body(W, ldW, Kd, lnb, pbv, out);
}

__global__ __launch_bounds__(256) void prep_bias_pool_k(const float* __restrict__ pw,
      const float* __restrict__ lb, const float* __restrict__ pb,
      float* __restrict__ Pbkv, float* __restrict__ Pbo){
  int j = blockIdx.x;
  const size_t MM = 1024ull*1024;
  int m = 1 + (j>>10), col = j&1023;
  const float* lnb = (m<3) ? lb + m*1024 : nullptr;
  float* out = (m==1)?(Pbkv+col) : (m==2)?(Pbkv+1024+col) : (Pbo+col);
  bias_body(pw + m*MM + col, 1024, 1024, lnb, pb[m*1024+col], out);
}

__global__ __launch_bounds__(256) void matvec_k(const float* __restrict__ xn, const float* __restrict__ W,
      int ldW, const float* __restrict__ bias, float* __restrict__ out){
  int j=blockIdx.x, tid=threadIdx.x;
  float s=0.f;
  for(int k=tid;k<1024;k+=256) s += xn[k]*W[(size_t)k*ldW + j];
  s=blockSum(s);
  if(tid==0) out[j]=s+bias[j];
}

// ---------------- GEMM: C[M,N] = A[M,K](bf16) * Bt[N,K](bf16) + bias ----------------
// BK=64: 32 MFMA + 16 ds_read + 8 gld16 per iteration, ONE barrier per iteration
// (half of BK=32). 2 bufs x 32KB = 64KB LDS -> 2 blocks/CU. Stage t+1 at top of
// iter t => full-iteration (~2000cy) latency cover. Rows are 64 u16 = 8 slots;
// T2 swizzle slot ^= row&7 (inverse-swizzled global source + swizzled ds_read).
template<int EPI,int OUTF,int TV>
__global__ __launch_bounds__(256) void gemm_k(const u16* __restrict__ A, const u16* __restrict__ Bt,
      const float* __restrict__ bias, const u16* __restrict__ resid, void* __restrict__ Cout,
      int M, int N, int K, int ldc){
  __shared__ u16 SH[32768];           // 2 bufs x (A 8192 + B 8192) u16 = 64 KB
  int tid = threadIdx.x, lane = tid&63, wv = tid>>6;
  int g = lane>>4, l15 = lane&15;
  int GX = gridDim.x;
  int nwg = GX*gridDim.y;
  int flat = blockIdx.y*GX + blockIdx.x;
  int q = nwg>>3, r = nwg&7, xcd = flat&7, idx = flat>>3;
  int f = (xcd<r ? xcd*(q+1) : r*(q+1)+(xcd-r)*q) + idx;
  int by = f/GX, bx = f - by*GX;
  int row0 = by*128, col0 = bx*128;
  int wr = wv>>1, wc = wv&1;
  int e0 = wv*512 + lane*8;
  f32x4 acc[4][4] = {};
  auto STAGE = [&](int buf, int t){
    u16* base = SH + buf*16384;
    int k0 = t<<6;
    #pragma unroll
    for(int c=0;c<4;c++){
      int e = c*2048 + e0;
      int row = e>>6;
      int slx = ((e>>3)&7) ^ (row&7);      // inverse-swizzled source slot
      gld16(A  + (size_t)(row0 + row)*K + (k0 + slx*8), &base[e]);
      gld16(Bt + (size_t)(col0 + row)*K + (k0 + slx*8), &base[8192 + e]);
    }
  };
  int nt = K>>6;
  STAGE(0, 0);
  VM0(); BAR(); SCHED0();
  #pragma unroll 2
  for(int t=0;t<nt;t++){
    int b = t&1;
    if(t+1<nt) STAGE(b^1, t+1);
    bf16x8 a[2][4], bb[2][4];
    #pragma unroll
    for(int ks=0;ks<2;ks++){
      #pragma unroll
      for(int m=0;m<4;m++){
        int ra = wr*64+m*16+l15;
        a[ks][m] = *(const bf16x8*)&SH[b*16384 + ra*64 + (((ks*4+g) ^ (ra&7))<<3)];
      }
      #pragma unroll
      for(int n=0;n<4;n++){
        int rb = wc*64+n*16+l15;
        bb[ks][n] = *(const bf16x8*)&SH[b*16384 + 8192 + rb*64 + (((ks*4+g) ^ (rb&7))<<3)];
      }
    }
    #pragma unroll
    for(int ks=0;ks<2;ks++)
      #pragma unroll
      for(int m=0;m<4;m++)
        #pragma unroll
        for(int n=0;n<4;n++)
          acc[m][n] = __builtin_amdgcn_mfma_f32_16x16x32_bf16(a[ks][m], bb[ks][n], acc[m][n], 0,0,0);
    if(t+1<nt){
      VM0(); LGKM0(); BAR(); SCHED0();
    }
  }
  if(TV){
    __syncthreads();
    u16* Tb = SH;
    #pragma unroll
    for(int m=0;m<4;m++){
      #pragma unroll
      for(int n=0;n<4;n++){
        int c = wc*64 + n*16 + l15;
        float bs = bias[col0 + c];
        #pragma unroll
        for(int r2=0;r2<4;r2++){
          int Rl = wr*64 + m*16 + g*4 + r2;
          Tb[c*128 + (Rl ^ ((c&7)<<4))] = f2b(acc[m][n][r2]+bs);
        }
      }
    }
    __syncthreads();
    for(int p=tid*4; p<16384; p+=1024){
      int c = p>>7, rr = p&127;
      int rs = rr ^ ((c&7)<<4);
      ushort4 v4;
      v4.x = Tb[c*128+rs]; v4.y = Tb[c*128+rs+1]; v4.z = Tb[c*128+rs+2]; v4.w = Tb[c*128+rs+3];
      *(ushort4*)((u16*)Cout + (size_t)(col0+c)*M + row0 + rr) = v4;
    }
  } else {
    #pragma unroll
    for(int m=0;m<4;m++){
      #pragma unroll
      for(int n=0;n<4;n++){
        int Cc = col0 + wc*64 + n*16 + l15;
        float bs = bias[Cc];
        #pragma unroll
        for(int r2=0;r2<4;r2++){
          int R = row0 + wr*64 + m*16 + g*4 + r2;
          float v = acc[m][n][r2] + bs;
          if(EPI==1) v = gelu_f(v);
          if(EPI==2) v += b2f(resid[(size_t)R*ldc + Cc]);
          if(OUTF) ((float*)Cout)[(size_t)R*ldc + Cc] = v;
          else     ((u16*)Cout)[(size_t)R*ldc + Cc] = f2b(v);
        }
      }
    }
  }
}

// ---------------- local block attention (S=128, dk=64), MFMA, T2-swizzled ----------------
__global__ __launch_bounds__(256) void attnl_k(const u16* __restrict__ QK, const u16* __restrict__ VT,
      u16* __restrict__ AT){
  __shared__ u16 SP[16384];
  __shared__ u16 Vt[8192];
  __shared__ float rmax[256], rsum[256];
  int tid=threadIdx.x, lane=tid&63, wv=tid>>6, g=lane>>4, l15=lane&15;
  int lb = blockIdx.x>>4, h = blockIdx.x&15;
  int wr=wv>>1, wc=wv&1;
  #pragma unroll
  for(int c=0;c<4;c++){
    int chunk = c*2048 + wv*512;
    int e = chunk + lane*8;
    int rq = e>>6;
    int sq = ((e>>3)&7) ^ (rq&7);
    int rv = e>>7;
    int sv = ((e>>3)&15) ^ (rv&15);
    gld16(QK + (size_t)(lb*128 + rq)*2048 + h*64 + sq*8,        &SP[chunk]);
    gld16(QK + (size_t)(lb*128 + rq)*2048 + 1024 + h*64 + sq*8, &SP[8192+chunk]);
    gld16(VT + (size_t)(h*64 + rv)*16384 + lb*128 + sv*8,       &Vt[chunk]);
  }
  __syncthreads();
  f32x4 s[4][4] = {};
  #pragma unroll
  for(int ks=0;ks<2;ks++){
    bf16x8 a[4], b[4];
    #pragma unroll
    for(int m=0;m<4;m++){
      int ra = wr*64+m*16+l15;
      a[m] = *(const bf16x8*)&SP[ra*64 + (((ks*4+g) ^ (ra&7))<<3)];
    }
    #pragma unroll
    for(int n=0;n<4;n++){
      int rb = wc*64+n*16+l15;
      b[n] = *(const bf16x8*)&SP[8192 + rb*64 + (((ks*4+g) ^ (rb&7))<<3)];
    }
    #pragma unroll
    for(int m=0;m<4;m++)
      #pragma unroll
      for(int n=0;n<4;n++)
        s[m][n] = __builtin_amdgcn_mfma_f32_16x16x32_bf16(a[m], b[n], s[m][n], 0,0,0);
  }
  #pragma unroll
  for(int m=0;m<4;m++)
    #pragma unroll
    for(int n=0;n<4;n++) s[m][n] *= 0.125f;
  #pragma unroll
  for(int m=0;m<4;m++)
    #pragma unroll
    for(int r=0;r<4;r++){
      float mx = fmaxf(fmaxf(s[m][0][r],s[m][1][r]),fmaxf(s[m][2][r],s[m][3][r]));
      #pragma unroll
      for(int msk=1;msk<16;msk<<=1) mx = fmaxf(mx, __shfl_xor(mx,msk,64));
      if(l15==0) rmax[(wr*64+m*16+g*4+r)*2+wc]=mx;
    }
  __syncthreads();
  #pragma unroll
  for(int m=0;m<4;m++)
    #pragma unroll
    for(int r=0;r<4;r++){
      int row = wr*64+m*16+g*4+r;
      float M2 = fmaxf(rmax[row*2], rmax[row*2+1]);
      float sm=0.f;
      #pragma unroll
      for(int n=0;n<4;n++){ float e = expf(s[m][n][r]-M2); s[m][n][r]=e; sm+=e; }
      #pragma unroll
      for(int msk=1;msk<16;msk<<=1) sm += __shfl_xor(sm,msk,64);
      if(l15==0) rsum[row*2+wc]=sm;
    }
  __syncthreads();
  #pragma unroll
  for(int m=0;m<4;m++)
    #pragma unroll
    for(int r=0;r<4;r++){
      int row = wr*64+m*16+g*4+r;
      float den = rsum[row*2]+rsum[row*2+1]+1e-9f;
      #pragma unroll
      for(int n=0;n<4;n++){
        float a = s[m][n][r]/den;
        a = fminf(fmaxf(a,1e-9f),1.f);
        int col = wc*64+n*16+l15;
        SP[row*128 + ((((col>>3) ^ (row&15))<<3) | (col&7))] = f2b(a);
      }
    }
  __syncthreads();
  f32x4 o[4][2] = {};
  #pragma unroll
  for(int ks=0;ks<4;ks++){
    bf16x8 a[4], b[2];
    #pragma unroll
    for(int m=0;m<4;m++){
      int ra = wr*64+m*16+l15;
      a[m] = *(const bf16x8*)&SP[ra*128 + (((ks*4+g) ^ (ra&15))<<3)];
    }
    #pragma unroll
    for(int n=0;n<2;n++){
      int rv = wc*32+n*16+l15;
      b[n] = *(const bf16x8*)&Vt[rv*128 + (((ks*4+g) ^ (rv&15))<<3)];
    }
    #pragma unroll
    for(int m=0;m<4;m++)
      #pragma unroll
      for(int n=0;n<2;n++)
        o[m][n] = __builtin_amdgcn_mfma_f32_16x16x32_bf16(a[m], b[n], o[m][n], 0,0,0);
  }
  #pragma unroll
  for(int m=0;m<4;m++)
    #pragma unroll
    for(int n=0;n<2;n++)
      #pragma unroll
      for(int r=0;r<4;r++)
        AT[(size_t)(lb*128 + wr*64+m*16+g*4+r)*1024 + h*64 + wc*32+n*16+l15] = f2b(o[m][n][r]);
}

// ---------------- pooling attention ----------------
__global__ __launch_bounds__(256) void poolattn_k(const float* __restrict__ qp, const u16* __restrict__ KV,
      u16* __restrict__ g0){
  int lb = blockIdx.x, tid = threadIdx.x;
  __shared__ float sc[16*128];
  for(int p=tid;p<2048;p+=256){
    int h=p>>7, j=p&127;
    const u16* krow = KV + (size_t)(lb*128+j)*2048 + h*64;
    float s=0.f;
    for(int d=0;d<64;d++) s += qp[h*64+d]*b2f(krow[d]);
    sc[h*128+j] = s*0.125f;
  }
  __syncthreads();
  if(tid<16){
    float* r=&sc[tid*128];
    float mx=r[0];
    for(int j=1;j<128;j++) mx=fmaxf(mx,r[j]);
    float sm=0.f;
    for(int j=0;j<128;j++){ float e=expf(r[j]-mx); r[j]=e; sm+=e; }
    sm+=1e-9f;
    for(int j=0;j<128;j++) r[j]=fminf(fmaxf(r[j]/sm,1e-9f),1.f);
  }
  __syncthreads();
  for(int c=tid;c<1024;c+=256){
    int h=c>>6;
    float acc=0.f;
    for(int j=0;j<128;j++) acc += sc[h*128+j]*b2f(KV[(size_t)(lb*128+j)*2048 + 1024 + c]);
    g0[(size_t)lb*1024 + c] = f2b(acc);
  }
}

// ---------------- global attention ----------------
__global__ __launch_bounds__(256) void attng_k(const u16* __restrict__ QKV, u16* __restrict__ OUT){
  int bb = blockIdx.x>>4, h = blockIdx.x&15;
  __shared__ float sc[32*32];
  int tid=threadIdx.x;
  for(int p=tid;p<1024;p+=256){
    int i=p>>5, j=p&31;
    const u16* q = QKV + (size_t)(bb*32+i)*3072 + h*64;
    const u16* k = QKV + (size_t)(bb*32+j)*3072 + 1024 + h*64;
    float s=0.f;
    for(int d=0;d<64;d++) s += b2f(q[d])*b2f(k[d]);
    sc[p] = s*0.125f;
  }
  __syncthreads();
  if(tid<32){
    float* r=&sc[tid*32];
    float mx=r[0];
    for(int j=1;j<32;j++) mx=fmaxf(mx,r[j]);
    float sm=0.f;
    for(int j=0;j<32;j++){ float e=expf(r[j]-mx); r[j]=e; sm+=e; }
    sm+=1e-9f;
    for(int j=0;j<32;j++) r[j]=fminf(fmaxf(r[j]/sm,1e-9f),1.f);
  }
  __syncthreads();
  for(int p=tid;p<2048;p+=256){
    int i=p>>6, d=p&63;
    float acc=0.f;
    for(int j=0;j<32;j++) acc += sc[i*32+j]*b2f(QKV[(size_t)(bb*32+j)*3072 + 2048 + h*64 + d]);
    OUT[(size_t)(bb*32+i)*1024 + h*64 + d] = f2b(acc);
  }
}

extern "C" void kernel_launch(void* const* d_in, const int* in_sizes, int n_in,
                              void* d_out, int out_size, void* d_ws, size_t ws_size,
                              hipStream_t stream) {
  (void)in_sizes; (void)n_in; (void)out_size;
  const void*  x       = d_in[0];
  const float* emb     = (const float*)d_in[1];
  const float* in_ln_w = (const float*)d_in[2];
  const float* in_ln_b = (const float*)d_in[3];
  const float* loc_ln_w= (const float*)d_in[4];
  const float* loc_ln_b= (const float*)d_in[5];
  const float* loc_pw  = (const float*)d_in[6];
  const float* loc_pb  = (const float*)d_in[7];
  const float* loc_w1  = (const float*)d_in[8];
  const float* loc_b1  = (const float*)d_in[9];
  const float* loc_w2  = (const float*)d_in[10];
  const float* loc_b2  = (const float*)d_in[11];
  const float* locn_w  = (const float*)d_in[12];
  const float* locn_b  = (const float*)d_in[13];
  const float* pool_q  = (const float*)d_in[14];
  const float* pool_n_w= (const float*)d_in[15];
  const float* pool_n_b= (const float*)d_in[16];
  const float* pool_ln_w=(const float*)d_in[17];
  const float* pool_ln_b=(const float*)d_in[18];
  const float* pool_pw = (const float*)d_in[19];
  const float* pool_pb = (const float*)d_in[20];
  const float* glob_ln_w=(const float*)d_in[21];
  const float* glob_ln_b=(const float*)d_in[22];
  const float* glob_pw = (const float*)d_in[23];
  const float* glob_pb = (const float*)d_in[24];
  const float* glob_w1 = (const float*)d_in[25];
  const float* glob_b1 = (const float*)d_in[26];
  const float* glob_w2 = (const float*)d_in[27];
  const float* glob_b2 = (const float*)d_in[28];
  const float* out_ln_w= (const float*)d_in[29];
  const float* out_ln_b= (const float*)d_in[30];
  const float* out_w   = (const float*)d_in[31];
  const float* out_b   = (const float*)d_in[32];

  char* wsb = (char*)d_ws;
  size_t off = 0;
  auto AL = [&](size_t n)->char*{ size_t o=(off+255)&~(size_t)255; off=o+n; return wsb+o; };

  int*  flag = (int*)AL(256);
  u16*  WA   = (u16*)AL(12ull*1024*1024*2);
  float* BA  = (float*)AL(12*1024*4);
  float* qn  = (float*)AL(1024*4);
  float* qp  = (float*)AL(1024*4);
  float* Hb  = (float*)AL(32000*4);
  u16*  R    = (u16*)AL(64ull*1024*1024*2);
  u16*  X    = (u16*)AL((size_t)NTOK*1024*2);
  u16*  XN   = (u16*)AL((size_t)NTOK*1024*2);
  u16*  G    = (u16*)AL(128ull*1024*2);
  u16*  GN   = (u16*)AL(128ull*1024*2);
  u16*  GQKV = (u16*)AL(128ull*3072*2);
  u16*  GAT  = (u16*)AL(128ull*1024*2);
  u16*  GO   = (u16*)AL(128ull*1024*2);
  u16*  GFH  = (u16*)AL(128ull*4096*2);
  u16*  g0   = (u16*)AL(128ull*1024*2);
  if(off > ws_size) return;

  u16 *LWqk = WA, *LWv = WA+2097152, *LWo = WA+3145728, *LW1 = WA+4194304, *LW2 = WA+8388608;
  float *Lbqk = BA, *Lbv = BA+2048, *Lbo = BA+3072, *Lb1 = BA+4096, *Lb2 = BA+8192;
  u16 *GWqkv = WA, *GWo = WA+3145728, *GW1 = WA+4194304, *GW2 = WA+8388608;
  float *Gbqkv = BA, *Gbo = BA+3072, *Gb1 = BA+4096, *Gb2 = BA+8192;
  u16 *PWkv = WA, *PWo = WA+2097152;
  float *Pbkv = BA, *Pbo = BA+2048;
  u16 *QKb = R, *VTb = R+33554432, *ATb = R+50331648;
  u16 *FH  = R;
  u16 *KVb = R;
  u16 *HW  = R;
  u16 *Ob  = XN;

  const size_t MM = 1024ull*1024;

  detect_k<<<1,256,0,stream>>>((const int*)x, flag);
  embed_k<<<NTOK,256,0,stream>>>(x, flag, emb, in_ln_w, in_ln_b, X, XN);

  for(int l=0;l<2;l++){
    const float* pw = loc_pw + (size_t)l*4*MM;
    const float* lw = loc_ln_w + (size_t)l*6*1024;
    const float* lb = loc_ln_b + (size_t)l*6*1024;
    const float* pb = loc_pb + (size_t)l*4*1024;
    const float* w1 = loc_w1 + (size_t)l*1024*4096;
    const float* w2 = loc_w2 + (size_t)l*4096*1024;
    prep_tf_layer_k<<<3072,256,0,stream>>>(pw, w1, w2, lw, LWqk, LWv, LWo, LW1, LW2);
    prep_bias_layer_k<<<9216,256,0,stream>>>(pw, w1, w2, lb, pb,
        loc_b1+(size_t)l*4096, loc_b2+(size_t)l*1024, Lbqk, Lbv, Lbo, Lb1, Lb2);

    gemm_k<0,0,0><<<dim3(16,128),256,0,stream>>>(XN, LWqk, Lbqk, nullptr, QKb, NTOK, 2048, 1024, 2048);
    gemm_k<0,0,1><<<dim3(8,128),256,0,stream>>>(XN, LWv, Lbv, nullptr, VTb, NTOK, 1024, 1024, 0);
    attnl_k<<<128*16,256,0,stream>>>(QKb, VTb, ATb);
    gemm_k<0,0,0><<<dim3(8,128),256,0,stream>>>(ATb, LWo, Lbo, nullptr, Ob, NTOK, 1024, 1024, 1024);
    ln_k<3,1><<<NTOK,256,0,stream>>>(Ob, X, lw+3*1024, lb+3*1024, X, XN);
    gemm_k<1,0,0><<<dim3(32,128),256,0,stream>>>(XN, LW1, Lb1, nullptr, FH, NTOK, 4096, 1024, 4096);
    gemm_k<2,0,0><<<dim3(8,128),256,0,stream>>>(FH, LW2, Lb2, X, Ob, NTOK, 1024, 4096, 1024);
    ln_k<2,1><<<NTOK,256,0,stream>>>(Ob, nullptr, lw+5*1024, lb+5*1024, X, XN);
  }

  prep_tf_pool_k<<<768,256,0,stream>>>(pool_pw, pool_ln_w, PWkv, PWo);
  prep_bias_pool_k<<<3072,256,0,stream>>>(pool_pw, pool_ln_b, pool_pb, Pbkv, Pbo);
  lnrow_k<<<1,256,0,stream>>>(pool_q, pool_ln_w, pool_ln_b, qn);
  matvec_k<<<1024,256,0,stream>>>(qn, pool_pw, 1024, pool_pb, qp);
  ln3x_k<<<NTOK,256,0,stream>>>(X, locn_w, locn_b, pool_n_w, pool_n_b, XN);
  gemm_k<0,0,0><<<dim3(16,128),256,0,stream>>>(XN, PWkv, Pbkv, nullptr, KVb, NTOK, 2048, 1024, 2048);
  poolattn_k<<<128,256,0,stream>>>(qp, KVb, g0);
  gemm_k<0,0,0><<<dim3(8,1),256,0,stream>>>(g0, PWo, Pbo, nullptr, GO, 128, 1024, 1024, 1024);
  ln_k<1,1><<<128,256,0,stream>>>(GO, nullptr, pool_ln_w+3*1024, pool_ln_b+3*1024, G, GN);

  for(int l=0;l<2;l++){
    const float* pw = glob_pw + (size_t)l*4*MM;
    const float* lw = glob_ln_w + (size_t)l*6*1024;
    const float* lb = glob_ln_b + (size_t)l*6*1024;
    const float* pb = glob_pb + (size_t)l*4*1024;
    const float* w1 = glob_w1 + (size_t)l*1024*4096;
    const float* w2 = glob_w2 + (size_t)l*4096*1024;
    prep_tf_layer_k<<<3072,256,0,stream>>>(pw, w1, w2, lw, GWqkv, GWqkv+2097152, GWo, GW1, GW2);
    prep_bias_layer_k<<<9216,256,0,stream>>>(pw, w1, w2, lb, pb,
        glob_b1+(size_t)l*4096, glob_b2+(size_t)l*1024, Gbqkv, Gbqkv+2048, Gbo, Gb1, Gb2);

    gemm_k<0,0,0><<<dim3(24,1),256,0,stream>>>(GN, GWqkv, Gbqkv, nullptr, GQKV, 128, 3072, 1024, 3072);
    attng_k<<<64,256,0,stream>>>(GQKV, GAT);
    gemm_k<0,0,0><<<dim3(8,1),256,0,stream>>>(GAT, GWo, Gbo, nullptr, GO, 128, 1024, 1024, 1024);
    ln_k<3,1><<<128,256,0,stream>>>(GO, G, lw+3*1024, lb+3*1024, G, GN);
    gemm_k<1,0,0><<<dim3(32,1),256,0,stream>>>(GN, GW1, Gb1, nullptr, GFH, 128, 4096, 1024, 4096);
    gemm_k<2,0,0><<<dim3(8,1),256,0,stream>>>(GFH, GW2, Gb2, G, GO, 128, 1024, 4096, 1024);
    ln_k<2,1><<<128,256,0,stream>>>(GO, nullptr, lw+5*1024, lb+5*1024, G, GN);
  }

  tf_k<<<dim3(500,16),256,0,stream>>>(out_w, 32000, out_ln_w, HW, 1024);
  bias_k<<<32000,256,0,stream>>>(out_w, 32000, out_ln_b, out_b, Hb, 1024);
  gemm_k<0,1,0><<<dim3(250,1),256,0,stream>>>(GN, HW, Hb, nullptr, d_out, 128, 32000, 1024, 32000);
}

// Round 10
// 1914.754 us; speedup vs baseline: 1.0949x; 1.0173x over previous
//
#include <hip/hip_runtime.h>
#include <hip/hip_bf16.h>
#include <math.h>

#define DEV __device__ __forceinline__

typedef __attribute__((ext_vector_type(8))) short bf16x8;
typedef __attribute__((ext_vector_type(4))) float f32x4;
typedef unsigned short u16;

constexpr int D_ = 1024, NTOK = 16384, SEQ = 4096;

DEV u16 f2b(float f){
  union{float f;unsigned u;} v; v.f=f;
  unsigned r = (v.u + 0x7fffu + ((v.u>>16)&1u))>>16;
  return (u16)r;
}
DEV float b2f(u16 h){ union{unsigned u;float f;} v; v.u=((unsigned)h)<<16; return v.f; }

DEV float gelu_f(float x){
  float z = 0.7978845608028654f*(x + 0.044715f*x*x*x);
  float e = __expf(-2.f*z);
  float t = 2.f/(1.f+e) - 1.f;
  return 0.5f*x*(1.f+t);
}

DEV void gld16(const void* g, void* l){
  __builtin_amdgcn_global_load_lds((const __attribute__((address_space(1))) void*)g,
                                   (__attribute__((address_space(3))) void*)l, 16, 0, 0);
}

#define BAR()    __builtin_amdgcn_s_barrier()
#define SCHED0() __builtin_amdgcn_sched_barrier(0)
#define LGKM0()  asm volatile("s_waitcnt lgkmcnt(0)" ::: "memory")
#define VM0()    asm volatile("s_waitcnt vmcnt(0)" ::: "memory")

DEV float blockSum(float v){
  __shared__ float sb[4];
  #pragma unroll
  for(int m=32;m>=1;m>>=1) v += __shfl_xor(v, m, 64);
  int lane = threadIdx.x & 63, wv = threadIdx.x >> 6;
  __syncthreads();
  if(lane==0) sb[wv]=v;
  __syncthreads();
  float r = sb[0]+sb[1]+sb[2]+sb[3];
  __syncthreads();
  return r;
}

// ---------------- token dtype detect: int64 vs int32 ----------------
__global__ __launch_bounds__(256) void detect_k(const int* __restrict__ xr, int* __restrict__ flag){
  int tid=threadIdx.x; float cnt=0.f;
  for(int i=tid;i<8192;i+=256) if(xr[2*i+1]!=0) cnt+=1.f;
  cnt = blockSum(cnt);
  if(tid==0) *flag = (cnt < 64.f) ? 1 : 0;
}

// ---------------- embed + PE + input LN (writes X and XN=norm(X)) ----------------
__global__ __launch_bounds__(256) void embed_k(const void* __restrict__ xv, const int* __restrict__ flag,
      const float* __restrict__ emb, const float* __restrict__ w, const float* __restrict__ b,
      u16* __restrict__ out, u16* __restrict__ outn){
  int t = blockIdx.x;
  int id;
  if(*flag) id = (int)((const long long*)xv)[t];
  else      id = ((const int*)xv)[t];
  int s = t & (SEQ-1);
  int d0 = threadIdx.x*4;
  float4 e4 = *(const float4*)(emb + (size_t)id*D_ + d0);
  float vv[4] = {e4.x, e4.y, e4.z, e4.w};
  float acc = 0.f;
  #pragma unroll
  for(int i=0;i<4;i++){
    float e = fminf(fmaxf(vv[i], -100.f), 100.f);
    int d = d0+i;
    float fr = expf(-(float)(d & ~1) * (9.210340371976184f/(float)D_));
    float ang = (float)s * fr;
    e += (d&1) ? cosf(ang) : sinf(ang);
    vv[i]=e; acc+=e;
  }
  float mean = blockSum(acc)*(1.f/D_);
  float var=0.f;
  #pragma unroll
  for(int i=0;i<4;i++){ float dd=vv[i]-mean; var+=dd*dd; }
  var = blockSum(var)*(1.f/D_);
  float rs = rsqrtf(var+1e-5f);
  float y[4];
  #pragma unroll
  for(int i=0;i<4;i++) y[i] = (vv[i]-mean)*rs*w[d0+i]+b[d0+i];
  ushort4 o; o.x=f2b(y[0]); o.y=f2b(y[1]); o.z=f2b(y[2]); o.w=f2b(y[3]);
  *(ushort4*)(out + (size_t)t*D_ + d0) = o;
  float m2 = blockSum(y[0]+y[1]+y[2]+y[3])*(1.f/D_);
  float v2=0.f;
  #pragma unroll
  for(int i=0;i<4;i++){ float dd=y[i]-m2; v2+=dd*dd; }
  v2 = blockSum(v2)*(1.f/D_);
  float rs2 = rsqrtf(v2+1e-5f);
  ushort4 on; on.x=f2b((y[0]-m2)*rs2); on.y=f2b((y[1]-m2)*rs2); on.z=f2b((y[2]-m2)*rs2); on.w=f2b((y[3]-m2)*rs2);
  *(ushort4*)(outn + (size_t)t*D_ + d0) = on;
}

// ---------------- LayerNorm family ----------------
template<int MODE,int WRN>
__global__ __launch_bounds__(256) void ln_k(const u16* __restrict__ in, const u16* __restrict__ res,
      const float* __restrict__ w, const float* __restrict__ b, u16* __restrict__ out,
      u16* __restrict__ outn){
  int t = blockIdx.x; int d0 = threadIdx.x*4;
  ushort4 r4 = *(const ushort4*)(in + (size_t)t*D_ + d0);
  float vv[4] = {b2f(r4.x),b2f(r4.y),b2f(r4.z),b2f(r4.w)};
  float mean = blockSum(vv[0]+vv[1]+vv[2]+vv[3])*(1.f/D_);
  float var=0.f;
  #pragma unroll
  for(int i=0;i<4;i++){ float dd=vv[i]-mean; var+=dd*dd; }
  var = blockSum(var)*(1.f/D_);
  float rs = rsqrtf(var+1e-5f);
  float rv[4]={0,0,0,0};
  if(MODE==3){
    ushort4 q4 = *(const ushort4*)(res + (size_t)t*D_ + d0);
    rv[0]=b2f(q4.x); rv[1]=b2f(q4.y); rv[2]=b2f(q4.z); rv[3]=b2f(q4.w);
  }
  float y[4];
  #pragma unroll
  for(int i=0;i<4;i++){
    float v = (vv[i]-mean)*rs;
    v = v*w[d0+i]+b[d0+i];
    if(MODE==2) v = fminf(fmaxf(v,-100.f),100.f);
    if(MODE==3) v += rv[i];
    y[i]=v;
  }
  ushort4 o; o.x=f2b(y[0]); o.y=f2b(y[1]); o.z=f2b(y[2]); o.w=f2b(y[3]);
  *(ushort4*)(out + (size_t)t*D_ + d0) = o;
  if(WRN){
    float m2 = blockSum(y[0]+y[1]+y[2]+y[3])*(1.f/D_);
    float v2=0.f;
    #pragma unroll
    for(int i=0;i<4;i++){ float dd=y[i]-m2; v2+=dd*dd; }
    v2 = blockSum(v2)*(1.f/D_);
    float rs2 = rsqrtf(v2+1e-5f);
    ushort4 on; on.x=f2b((y[0]-m2)*rs2); on.y=f2b((y[1]-m2)*rs2); on.z=f2b((y[2]-m2)*rs2); on.w=f2b((y[3]-m2)*rs2);
    *(ushort4*)(outn + (size_t)t*D_ + d0) = on;
  }
}

__global__ __launch_bounds__(256) void ln3x_k(const u16* __restrict__ in,
    const float* __restrict__ w1,const float* __restrict__ b1,
    const float* __restrict__ w2,const float* __restrict__ b2, u16* __restrict__ out){
  int t=blockIdx.x, d0=threadIdx.x*4;
  ushort4 r4 = *(const ushort4*)(in + (size_t)t*D_ + d0);
  float vv[4]={b2f(r4.x),b2f(r4.y),b2f(r4.z),b2f(r4.w)};
  #pragma unroll
  for(int pass=0;pass<3;pass++){
    float mean = blockSum(vv[0]+vv[1]+vv[2]+vv[3])*(1.f/D_);
    float var=0.f;
    #pragma unroll
    for(int i=0;i<4;i++){ float dd=vv[i]-mean; var+=dd*dd; }
    var = blockSum(var)*(1.f/D_);
    float rs = rsqrtf(var+1e-5f);
    #pragma unroll
    for(int i=0;i<4;i++){
      float y=(vv[i]-mean)*rs;
      if(pass==0) y = y*w1[d0+i]+b1[d0+i];
      else if(pass==1) y = y*w2[d0+i]+b2[d0+i];
      vv[i]=y;
    }
  }
  ushort4 o;
  o.x=f2b(vv[0]); o.y=f2b(vv[1]); o.z=f2b(vv[2]); o.w=f2b(vv[3]);
  *(ushort4*)(out + (size_t)t*D_ + d0) = o;
}

__global__ __launch_bounds__(256) void lnrow_k(const float* __restrict__ x, const float* __restrict__ w,
      const float* __restrict__ b, float* __restrict__ out){
  int d0=threadIdx.x*4;
  float vv[4]={x[d0],x[d0+1],x[d0+2],x[d0+3]};
  float mean = blockSum(vv[0]+vv[1]+vv[2]+vv[3])*(1.f/D_);
  float var=0.f;
  #pragma unroll
  for(int i=0;i<4;i++){ float dd=vv[i]-mean; var+=dd*dd; }
  var = blockSum(var)*(1.f/D_);
  float rs = rsqrtf(var+1e-5f);
  #pragma unroll
  for(int i=0;i<4;i++) out[d0+i]=(vv[i]-mean)*rs*w[d0+i]+b[d0+i];
}

// ---------------- 64x64 transpose body macro ----------------
#define TF_BODY(W, ldW, lnw, Wt, Kd, n0, k0)                                 \
  {                                                                          \
    int ty = threadIdx.x>>6, tx = threadIdx.x&63;                            \
    _Pragma("unroll")                                                        \
    for(int p=0;p<16;p++){                                                   \
      int row = p*4+ty;                                                      \
      float sc = (lnw) ? (lnw)[(k0)+row] : 1.f;                              \
      T[row][tx] = (W)[(size_t)((k0)+row)*(ldW) + (n0)+tx]*sc;               \
    }                                                                        \
    __syncthreads();                                                         \
    _Pragma("unroll")                                                        \
    for(int p=0;p<16;p++){                                                   \
      int row = p*4+ty;                                                      \
      (Wt)[(size_t)((n0)+row)*(Kd) + (k0)+tx] = f2b(T[tx][row]);             \
    }                                                                        \
  }

__global__ __launch_bounds__(256) void tf_k(const float* __restrict__ W, int ldW,
      const float* __restrict__ lnw, u16* __restrict__ Wt, int Kd){
  __shared__ float T[64][65];
  int n0 = blockIdx.x*64, k0 = blockIdx.y*64;
  TF_BODY(W, ldW, lnw, Wt, Kd, n0, k0)
}

__global__ __launch_bounds__(256) void prep_tf_layer_k(const float* __restrict__ pw,
      const float* __restrict__ w1, const float* __restrict__ w2, const float* __restrict__ lw,
      u16* __restrict__ Wqk, u16* __restrict__ Wv, u16* __restrict__ Wo,
      u16* __restrict__ W1t, u16* __restrict__ W2t){
  __shared__ float T[64][65];
  int bid = blockIdx.x;
  const float* W; int ldW; const float* lnw; u16* Wt; int Kd, n0, k0;
  if(bid < 1024){
    int m = bid>>8, t = bid&255;
    n0 = (t&15)*64; k0 = (t>>4)*64;
    W = pw + (size_t)m*1024*1024; ldW = 1024; Kd = 1024;
    lnw = (m<3) ? lw + m*1024 : nullptr;
    Wt = (m==0)?Wqk : (m==1)?(Wqk+1024*1024) : (m==2)?Wv : Wo;
  } else if(bid < 2048){
    int t = bid-1024;
    n0 = (t&63)*64; k0 = (t>>6)*64;
    W = w1; ldW = 4096; Kd = 1024; lnw = lw+4*1024; Wt = W1t;
  } else {
    int t = bid-2048;
    n0 = (t&15)*64; k0 = (t>>4)*64;
    W = w2; ldW = 1024; Kd = 4096; lnw = nullptr; Wt = W2t;
  }
  TF_BODY(W, ldW, lnw, Wt, Kd, n0, k0)
}

__global__ __launch_bounds__(256) void prep_tf_pool_k(const float* __restrict__ pw,
      const float* __restrict__ lw, u16* __restrict__ PWkv, u16* __restrict__ PWo){
  __shared__ float T[64][65];
  int bid = blockIdx.x;
  int m = 1 + (bid>>8), t = bid&255;
  int n0 = (t&15)*64, k0 = (t>>4)*64;
  const float* W = pw + (size_t)m*1024*1024;
  const float* lnw = (m<3) ? lw + m*1024 : nullptr;
  u16* Wt = (m==1)?PWkv : (m==2)?(PWkv+1024*1024) : PWo;
  TF_BODY(W, 1024, lnw, Wt, 1024, n0, k0)
}

// ---------------- bias fold ----------------
DEV void bias_body(const float* W, int ldW, int Kd, const float* lnb, float pbv, float* out){
  int tid = threadIdx.x;
  float chk = 0.f;
  if(lnb){ for(int k=tid;k<Kd;k+=256) chk += fabsf(lnb[k]); }
  chk = blockSum(chk);
  if(chk==0.f){ if(tid==0) *out = pbv; return; }
  float s=0.f;
  for(int k=tid;k<Kd;k+=256) s += lnb[k]*W[(size_t)k*ldW];
  s = blockSum(s);
  if(tid==0) *out = pbv + s;
}

__global__ __launch_bounds__(256) void bias_k(const float* __restrict__ W, int ldW,
      const float* __restrict__ lnb, const float* __restrict__ pb, float* __restrict__ out, int Kd){
  int j = blockIdx.x;
  bias_body(W + j, ldW, Kd, lnb, pb[j], out + j);
}

__global__ __launch_bounds__(256) void prep_bias_layer_k(const float* __restrict__ pw,
      const float* __restrict__ w1, const float* __restrict__ w2,
      const float* __restrict__ lb, const float* __restrict__ pb,
      const float* __restrict__ b1in, const float* __restrict__ b2in,
      float* __restrict__ Bqk, float* __restrict__ Bv, float* __restrict__ Bo,
      float* __restrict__ B1, float* __restrict__ B2){
  int j = blockIdx.x;
  const float* W; int ldW, Kd; const float* lnb; float pbv; float* out;
  const size_t MM = 1024ull*1024;
  if(j<2048){ int m=j>>10; int col=j&1023; W=pw+m*MM+col; ldW=1024; Kd=1024; lnb=lb+m*1024; pbv=pb[m*1024+col]; out=Bqk+j; }
  else if(j<3072){ int col=j-2048; W=pw+2*MM+col; ldW=1024; Kd=1024; lnb=lb+2*1024; pbv=pb[2*1024+col]; out=Bv+col; }
  else if(j<4096){ int col=j-3072; W=pw+3*MM+col; ldW=1024; Kd=1024; lnb=nullptr; pbv=pb[3*1024+col]; out=Bo+col; }
  else if(j<8192){ int col=j-4096; W=w1+col; ldW=4096; Kd=1024; lnb=lb+4*1024; pbv=b1in[col]; out=B1+col; }
  else { int col=j-8192; W=w2+col; ldW=1024; Kd=4096; lnb=nullptr; pbv=b2in[col]; out=B2+col; }
  bias_body(W, ldW, Kd, lnb, pbv, out);
}

__global__ __launch_bounds__(256) void prep_bias_pool_k(const float* __restrict__ pw,
      const float* __restrict__ lb, const float* __restrict__ pb,
      float* __restrict__ Pbkv, float* __restrict__ Pbo){
  int j = blockIdx.x;
  const size_t MM = 1024ull*1024;
  int m = 1 + (j>>10), col = j&1023;
  const float* lnb = (m<3) ? lb + m*1024 : nullptr;
  float* out = (m==1)?(Pbkv+col) : (m==2)?(Pbkv+1024+col) : (Pbo+col);
  bias_body(pw + m*MM + col, 1024, 1024, lnb, pb[m*1024+col], out);
}

__global__ __launch_bounds__(256) void matvec_k(const float* __restrict__ xn, const float* __restrict__ W,
      int ldW, const float* __restrict__ bias, float* __restrict__ out){
  int j=blockIdx.x, tid=threadIdx.x;
  float s=0.f;
  for(int k=tid;k<1024;k+=256) s += xn[k]*W[(size_t)k*ldW + j];
  s=blockSum(s);
  if(tid==0) out[j]=s+bias[j];
}

// ---------------- GEMM: C[M,N] = A[M,K](bf16) * Bt[N,K](bf16) + bias ----------------
// BK=64 double-buffered (r9 structure) + L2-supertile block order: within the
// XCD-contiguous chunk, blocks iterate 8-row supertiles so the ~64 concurrent
// blocks/XCD cover 8 A-panels + 8 B-panels (4 MB = L2) instead of 2x32 (8.5 MB).
template<int EPI,int OUTF,int TV>
__global__ __launch_bounds__(256) void gemm_k(const u16* __restrict__ A, const u16* __restrict__ Bt,
      const float* __restrict__ bias, const u16* __restrict__ resid, void* __restrict__ Cout,
      int M, int N, int K, int ldc){
  __shared__ u16 SH[32768];           // 2 bufs x (A 8192 + B 8192) u16 = 64 KB
  int tid = threadIdx.x, lane = tid&63, wv = tid>>6;
  int g = lane>>4, l15 = lane&15;
  int GX = gridDim.x, GY = gridDim.y;
  int nwg = GX*GY;
  int flat = blockIdx.y*GX + blockIdx.x;
  int q = nwg>>3, r = nwg&7, xcd = flat&7, idx = flat>>3;
  int f = (xcd<r ? xcd*(q+1) : r*(q+1)+(xcd-r)*q) + idx;
  int by, bx;
  if((GY & 7) == 0){
    int sbs = GX<<3;                  // supertile = 8 rows x GX cols
    int s = f / sbs, rr2 = f - s*sbs;
    by = s*8 + (rr2 & 7);
    bx = rr2 >> 3;
  } else {
    by = f/GX; bx = f - by*GX;
  }
  int row0 = by*128, col0 = bx*128;
  int wr = wv>>1, wc = wv&1;
  int e0 = wv*512 + lane*8;
  f32x4 acc[4][4] = {};
  auto STAGE = [&](int buf, int t){
    u16* base = SH + buf*16384;
    int k0 = t<<6;
    #pragma unroll
    for(int c=0;c<4;c++){
      int e = c*2048 + e0;
      int row = e>>6;
      int slx = ((e>>3)&7) ^ (row&7);      // inverse-swizzled source slot
      gld16(A  + (size_t)(row0 + row)*K + (k0 + slx*8), &base[e]);
      gld16(Bt + (size_t)(col0 + row)*K + (k0 + slx*8), &base[8192 + e]);
    }
  };
  int nt = K>>6;
  STAGE(0, 0);
  VM0(); BAR(); SCHED0();
  #pragma unroll 2
  for(int t=0;t<nt;t++){
    int b = t&1;
    if(t+1<nt) STAGE(b^1, t+1);
    bf16x8 a[2][4], bb[2][4];
    #pragma unroll
    for(int ks=0;ks<2;ks++){
      #pragma unroll
      for(int m=0;m<4;m++){
        int ra = wr*64+m*16+l15;
        a[ks][m] = *(const bf16x8*)&SH[b*16384 + ra*64 + (((ks*4+g) ^ (ra&7))<<3)];
      }
      #pragma unroll
      for(int n=0;n<4;n++){
        int rb = wc*64+n*16+l15;
        bb[ks][n] = *(const bf16x8*)&SH[b*16384 + 8192 + rb*64 + (((ks*4+g) ^ (rb&7))<<3)];
      }
    }
    #pragma unroll
    for(int ks=0;ks<2;ks++)
      #pragma unroll
      for(int m=0;m<4;m++)
        #pragma unroll
        for(int n=0;n<4;n++)
          acc[m][n] = __builtin_amdgcn_mfma_f32_16x16x32_bf16(a[ks][m], bb[ks][n], acc[m][n], 0,0,0);
    if(t+1<nt){
      VM0(); LGKM0(); BAR(); SCHED0();
    }
  }
  if(TV){
    __syncthreads();
    u16* Tb = SH;
    #pragma unroll
    for(int m=0;m<4;m++){
      #pragma unroll
      for(int n=0;n<4;n++){
        int c = wc*64 + n*16 + l15;
        float bs = bias[col0 + c];
        #pragma unroll
        for(int r2=0;r2<4;r2++){
          int Rl = wr*64 + m*16 + g*4 + r2;
          Tb[c*128 + (Rl ^ ((c&7)<<4))] = f2b(acc[m][n][r2]+bs);
        }
      }
    }
    __syncthreads();
    for(int p=tid*4; p<16384; p+=1024){
      int c = p>>7, rr = p&127;
      int rs = rr ^ ((c&7)<<4);
      ushort4 v4;
      v4.x = Tb[c*128+rs]; v4.y = Tb[c*128+rs+1]; v4.z = Tb[c*128+rs+2]; v4.w = Tb[c*128+rs+3];
      *(ushort4*)((u16*)Cout + (size_t)(col0+c)*M + row0 + rr) = v4;
    }
  } else {
    #pragma unroll
    for(int m=0;m<4;m++){
      #pragma unroll
      for(int n=0;n<4;n++){
        int Cc = col0 + wc*64 + n*16 + l15;
        float bs = bias[Cc];
        #pragma unroll
        for(int r2=0;r2<4;r2++){
          int R = row0 + wr*64 + m*16 + g*4 + r2;
          float v = acc[m][n][r2] + bs;
          if(EPI==1) v = gelu_f(v);
          if(EPI==2) v += b2f(resid[(size_t)R*ldc + Cc]);
          if(OUTF) ((float*)Cout)[(size_t)R*ldc + Cc] = v;
          else     ((u16*)Cout)[(size_t)R*ldc + Cc] = f2b(v);
        }
      }
    }
  }
}

// ---------------- local block attention (S=128, dk=64), MFMA, T2-swizzled ----------------
__global__ __launch_bounds__(256) void attnl_k(const u16* __restrict__ QK, const u16* __restrict__ VT,
      u16* __restrict__ AT){
  __shared__ u16 SP[16384];
  __shared__ u16 Vt[8192];
  __shared__ float rmax[256], rsum[256];
  int tid=threadIdx.x, lane=tid&63, wv=tid>>6, g=lane>>4, l15=lane&15;
  int lb = blockIdx.x>>4, h = blockIdx.x&15;
  int wr=wv>>1, wc=wv&1;
  #pragma unroll
  for(int c=0;c<4;c++){
    int chunk = c*2048 + wv*512;
    int e = chunk + lane*8;
    int rq = e>>6;
    int sq = ((e>>3)&7) ^ (rq&7);
    int rv = e>>7;
    int sv = ((e>>3)&15) ^ (rv&15);
    gld16(QK + (size_t)(lb*128 + rq)*2048 + h*64 + sq*8,        &SP[chunk]);
    gld16(QK + (size_t)(lb*128 + rq)*2048 + 1024 + h*64 + sq*8, &SP[8192+chunk]);
    gld16(VT + (size_t)(h*64 + rv)*16384 + lb*128 + sv*8,       &Vt[chunk]);
  }
  __syncthreads();
  f32x4 s[4][4] = {};
  #pragma unroll
  for(int ks=0;ks<2;ks++){
    bf16x8 a[4], b[4];
    #pragma unroll
    for(int m=0;m<4;m++){
      int ra = wr*64+m*16+l15;
      a[m] = *(const bf16x8*)&SP[ra*64 + (((ks*4+g) ^ (ra&7))<<3)];
    }
    #pragma unroll
    for(int n=0;n<4;n++){
      int rb = wc*64+n*16+l15;
      b[n] = *(const bf16x8*)&SP[8192 + rb*64 + (((ks*4+g) ^ (rb&7))<<3)];
    }
    #pragma unroll
    for(int m=0;m<4;m++)
      #pragma unroll
      for(int n=0;n<4;n++)
        s[m][n] = __builtin_amdgcn_mfma_f32_16x16x32_bf16(a[m], b[n], s[m][n], 0,0,0);
  }
  #pragma unroll
  for(int m=0;m<4;m++)
    #pragma unroll
    for(int n=0;n<4;n++) s[m][n] *= 0.125f;
  #pragma unroll
  for(int m=0;m<4;m++)
    #pragma unroll
    for(int r=0;r<4;r++){
      float mx = fmaxf(fmaxf(s[m][0][r],s[m][1][r]),fmaxf(s[m][2][r],s[m][3][r]));
      #pragma unroll
      for(int msk=1;msk<16;msk<<=1) mx = fmaxf(mx, __shfl_xor(mx,msk,64));
      if(l15==0) rmax[(wr*64+m*16+g*4+r)*2+wc]=mx;
    }
  __syncthreads();
  #pragma unroll
  for(int m=0;m<4;m++)
    #pragma unroll
    for(int r=0;r<4;r++){
      int row = wr*64+m*16+g*4+r;
      float M2 = fmaxf(rmax[row*2], rmax[row*2+1]);
      float sm=0.f;
      #pragma unroll
      for(int n=0;n<4;n++){ float e = expf(s[m][n][r]-M2); s[m][n][r]=e; sm+=e; }
      #pragma unroll
      for(int msk=1;msk<16;msk<<=1) sm += __shfl_xor(sm,msk,64);
      if(l15==0) rsum[row*2+wc]=sm;
    }
  __syncthreads();
  #pragma unroll
  for(int m=0;m<4;m++)
    #pragma unroll
    for(int r=0;r<4;r++){
      int row = wr*64+m*16+g*4+r;
      float den = rsum[row*2]+rsum[row*2+1]+1e-9f;
      #pragma unroll
      for(int n=0;n<4;n++){
        float a = s[m][n][r]/den;
        a = fminf(fmaxf(a,1e-9f),1.f);
        int col = wc*64+n*16+l15;
        SP[row*128 + ((((col>>3) ^ (row&15))<<3) | (col&7))] = f2b(a);
      }
    }
  __syncthreads();
  f32x4 o[4][2] = {};
  #pragma unroll
  for(int ks=0;ks<4;ks++){
    bf16x8 a[4], b[2];
    #pragma unroll
    for(int m=0;m<4;m++){
      int ra = wr*64+m*16+l15;
      a[m] = *(const bf16x8*)&SP[ra*128 + (((ks*4+g) ^ (ra&15))<<3)];
    }
    #pragma unroll
    for(int n=0;n<2;n++){
      int rv = wc*32+n*16+l15;
      b[n] = *(const bf16x8*)&Vt[rv*128 + (((ks*4+g) ^ (rv&15))<<3)];
    }
    #pragma unroll
    for(int m=0;m<4;m++)
      #pragma unroll
      for(int n=0;n<2;n++)
        o[m][n] = __builtin_amdgcn_mfma_f32_16x16x32_bf16(a[m], b[n], o[m][n], 0,0,0);
  }
  #pragma unroll
  for(int m=0;m<4;m++)
    #pragma unroll
    for(int n=0;n<2;n++)
      #pragma unroll
      for(int r=0;r<4;r++)
        AT[(size_t)(lb*128 + wr*64+m*16+g*4+r)*1024 + h*64 + wc*32+n*16+l15] = f2b(o[m][n][r]);
}

// ---------------- pooling attention ----------------
__global__ __launch_bounds__(256) void poolattn_k(const float* __restrict__ qp, const u16* __restrict__ KV,
      u16* __restrict__ g0){
  int lb = blockIdx.x, tid = threadIdx.x;
  __shared__ float sc[16*128];
  for(int p=tid;p<2048;p+=256){
    int h=p>>7, j=p&127;
    const u16* krow = KV + (size_t)(lb*128+j)*2048 + h*64;
    float s=0.f;
    for(int d=0;d<64;d++) s += qp[h*64+d]*b2f(krow[d]);
    sc[h*128+j] = s*0.125f;
  }
  __syncthreads();
  if(tid<16){
    float* r=&sc[tid*128];
    float mx=r[0];
    for(int j=1;j<128;j++) mx=fmaxf(mx,r[j]);
    float sm=0.f;
    for(int j=0;j<128;j++){ float e=expf(r[j]-mx); r[j]=e; sm+=e; }
    sm+=1e-9f;
    for(int j=0;j<128;j++) r[j]=fminf(fmaxf(r[j]/sm,1e-9f),1.f);
  }
  __syncthreads();
  for(int c=tid;c<1024;c+=256){
    int h=c>>6;
    float acc=0.f;
    for(int j=0;j<128;j++) acc += sc[h*128+j]*b2f(KV[(size_t)(lb*128+j)*2048 + 1024 + c]);
    g0[(size_t)lb*1024 + c] = f2b(acc);
  }
}

// ---------------- global attention ----------------
__global__ __launch_bounds__(256) void attng_k(const u16* __restrict__ QKV, u16* __restrict__ OUT){
  int bb = blockIdx.x>>4, h = blockIdx.x&15;
  __shared__ float sc[32*32];
  int tid=threadIdx.x;
  for(int p=tid;p<1024;p+=256){
    int i=p>>5, j=p&31;
    const u16* q = QKV + (size_t)(bb*32+i)*3072 + h*64;
    const u16* k = QKV + (size_t)(bb*32+j)*3072 + 1024 + h*64;
    float s=0.f;
    for(int d=0;d<64;d++) s += b2f(q[d])*b2f(k[d]);
    sc[p] = s*0.125f;
  }
  __syncthreads();
  if(tid<32){
    float* r=&sc[tid*32];
    float mx=r[0];
    for(int j=1;j<32;j++) mx=fmaxf(mx,r[j]);
    float sm=0.f;
    for(int j=0;j<32;j++){ float e=expf(r[j]-mx); r[j]=e; sm+=e; }
    sm+=1e-9f;
    for(int j=0;j<32;j++) r[j]=fminf(fmaxf(r[j]/sm,1e-9f),1.f);
  }
  __syncthreads();
  for(int p=tid;p<2048;p+=256){
    int i=p>>6, d=p&63;
    float acc=0.f;
    for(int j=0;j<32;j++) acc += sc[i*32+j]*b2f(QKV[(size_t)(bb*32+j)*3072 + 2048 + h*64 + d]);
    OUT[(size_t)(bb*32+i)*1024 + h*64 + d] = f2b(acc);
  }
}

extern "C" void kernel_launch(void* const* d_in, const int* in_sizes, int n_in,
                              void* d_out, int out_size, void* d_ws, size_t ws_size,
                              hipStream_t stream) {
  (void)in_sizes; (void)n_in; (void)out_size;
  const void*  x       = d_in[0];
  const float* emb     = (const float*)d_in[1];
  const float* in_ln_w = (const float*)d_in[2];
  const float* in_ln_b = (const float*)d_in[3];
  const float* loc_ln_w= (const float*)d_in[4];
  const float* loc_ln_b= (const float*)d_in[5];
  const float* loc_pw  = (const float*)d_in[6];
  const float* loc_pb  = (const float*)d_in[7];
  const float* loc_w1  = (const float*)d_in[8];
  const float* loc_b1  = (const float*)d_in[9];
  const float* loc_w2  = (const float*)d_in[10];
  const float* loc_b2  = (const float*)d_in[11];
  const float* locn_w  = (const float*)d_in[12];
  const float* locn_b  = (const float*)d_in[13];
  const float* pool_q  = (const float*)d_in[14];
  const float* pool_n_w= (const float*)d_in[15];
  const float* pool_n_b= (const float*)d_in[16];
  const float* pool_ln_w=(const float*)d_in[17];
  const float* pool_ln_b=(const float*)d_in[18];
  const float* pool_pw = (const float*)d_in[19];
  const float* pool_pb = (const float*)d_in[20];
  const float* glob_ln_w=(const float*)d_in[21];
  const float* glob_ln_b=(const float*)d_in[22];
  const float* glob_pw = (const float*)d_in[23];
  const float* glob_pb = (const float*)d_in[24];
  const float* glob_w1 = (const float*)d_in[25];
  const float* glob_b1 = (const float*)d_in[26];
  const float* glob_w2 = (const float*)d_in[27];
  const float* glob_b2 = (const float*)d_in[28];
  const float* out_ln_w= (const float*)d_in[29];
  const float* out_ln_b= (const float*)d_in[30];
  const float* out_w   = (const float*)d_in[31];
  const float* out_b   = (const float*)d_in[32];

  char* wsb = (char*)d_ws;
  size_t off = 0;
  auto AL = [&](size_t n)->char*{ size_t o=(off+255)&~(size_t)255; off=o+n; return wsb+o; };

  int*  flag = (int*)AL(256);
  u16*  WA   = (u16*)AL(12ull*1024*1024*2);
  float* BA  = (float*)AL(12*1024*4);
  float* qn  = (float*)AL(1024*4);
  float* qp  = (float*)AL(1024*4);
  float* Hb  = (float*)AL(32000*4);
  u16*  R    = (u16*)AL(64ull*1024*1024*2);
  u16*  X    = (u16*)AL((size_t)NTOK*1024*2);
  u16*  XN   = (u16*)AL((size_t)NTOK*1024*2);
  u16*  G    = (u16*)AL(128ull*1024*2);
  u16*  GN   = (u16*)AL(128ull*1024*2);
  u16*  GQKV = (u16*)AL(128ull*3072*2);
  u16*  GAT  = (u16*)AL(128ull*1024*2);
  u16*  GO   = (u16*)AL(128ull*1024*2);
  u16*  GFH  = (u16*)AL(128ull*4096*2);
  u16*  g0   = (u16*)AL(128ull*1024*2);
  if(off > ws_size) return;

  u16 *LWqk = WA, *LWv = WA+2097152, *LWo = WA+3145728, *LW1 = WA+4194304, *LW2 = WA+8388608;
  float *Lbqk = BA, *Lbv = BA+2048, *Lbo = BA+3072, *Lb1 = BA+4096, *Lb2 = BA+8192;
  u16 *GWqkv = WA, *GWo = WA+3145728, *GW1 = WA+4194304, *GW2 = WA+8388608;
  float *Gbqkv = BA, *Gbo = BA+3072, *Gb1 = BA+4096, *Gb2 = BA+8192;
  u16 *PWkv = WA, *PWo = WA+2097152;
  float *Pbkv = BA, *Pbo = BA+2048;
  u16 *QKb = R, *VTb = R+33554432, *ATb = R+50331648;
  u16 *FH  = R;
  u16 *KVb = R;
  u16 *HW  = R;
  u16 *Ob  = XN;

  const size_t MM = 1024ull*1024;

  detect_k<<<1,256,0,stream>>>((const int*)x, flag);
  embed_k<<<NTOK,256,0,stream>>>(x, flag, emb, in_ln_w, in_ln_b, X, XN);

  for(int l=0;l<2;l++){
    const float* pw = loc_pw + (size_t)l*4*MM;
    const float* lw = loc_ln_w + (size_t)l*6*1024;
    const float* lb = loc_ln_b + (size_t)l*6*1024;
    const float* pb = loc_pb + (size_t)l*4*1024;
    const float* w1 = loc_w1 + (size_t)l*1024*4096;
    const float* w2 = loc_w2 + (size_t)l*4096*1024;
    prep_tf_layer_k<<<3072,256,0,stream>>>(pw, w1, w2, lw, LWqk, LWv, LWo, LW1, LW2);
    prep_bias_layer_k<<<9216,256,0,stream>>>(pw, w1, w2, lb, pb,
        loc_b1+(size_t)l*4096, loc_b2+(size_t)l*1024, Lbqk, Lbv, Lbo, Lb1, Lb2);

    gemm_k<0,0,0><<<dim3(16,128),256,0,stream>>>(XN, LWqk, Lbqk, nullptr, QKb, NTOK, 2048, 1024, 2048);
    gemm_k<0,0,1><<<dim3(8,128),256,0,stream>>>(XN, LWv, Lbv, nullptr, VTb, NTOK, 1024, 1024, 0);
    attnl_k<<<128*16,256,0,stream>>>(QKb, VTb, ATb);
    gemm_k<0,0,0><<<dim3(8,128),256,0,stream>>>(ATb, LWo, Lbo, nullptr, Ob, NTOK, 1024, 1024, 1024);
    ln_k<3,1><<<NTOK,256,0,stream>>>(Ob, X, lw+3*1024, lb+3*1024, X, XN);
    gemm_k<1,0,0><<<dim3(32,128),256,0,stream>>>(XN, LW1, Lb1, nullptr, FH, NTOK, 4096, 1024, 4096);
    gemm_k<2,0,0><<<dim3(8,128),256,0,stream>>>(FH, LW2, Lb2, X, Ob, NTOK, 1024, 4096, 1024);
    ln_k<2,1><<<NTOK,256,0,stream>>>(Ob, nullptr, lw+5*1024, lb+5*1024, X, XN);
  }

  prep_tf_pool_k<<<768,256,0,stream>>>(pool_pw, pool_ln_w, PWkv, PWo);
  prep_bias_pool_k<<<3072,256,0,stream>>>(pool_pw, pool_ln_b, pool_pb, Pbkv, Pbo);
  lnrow_k<<<1,256,0,stream>>>(pool_q, pool_ln_w, pool_ln_b, qn);
  matvec_k<<<1024,256,0,stream>>>(qn, pool_pw, 1024, pool_pb, qp);
  ln3x_k<<<NTOK,256,0,stream>>>(X, locn_w, locn_b, pool_n_w, pool_n_b, XN);
  gemm_k<0,0,0><<<dim3(16,128),256,0,stream>>>(XN, PWkv, Pbkv, nullptr, KVb, NTOK, 2048, 1024, 2048);
  poolattn_k<<<128,256,0,stream>>>(qp, KVb, g0);
  gemm_k<0,0,0><<<dim3(8,1),256,0,stream>>>(g0, PWo, Pbo, nullptr, GO, 128, 1024, 1024, 1024);
  ln_k<1,1><<<128,256,0,stream>>>(GO, nullptr, pool_ln_w+3*1024, pool_ln_b+3*1024, G, GN);

  for(int l=0;l<2;l++){
    const float* pw = glob_pw + (size_t)l*4*MM;
    const float* lw = glob_ln_w + (size_t)l*6*1024;
    const float* lb = glob_ln_b + (size_t)l*6*1024;
    const float* pb = glob_pb + (size_t)l*4*1024;
    const float* w1 = glob_w1 + (size_t)l*1024*4096;
    const float* w2 = glob_w2 + (size_t)l*4096*1024;
    prep_tf_layer_k<<<3072,256,0,stream>>>(pw, w1, w2, lw, GWqkv, GWqkv+2097152, GWo, GW1, GW2);
    prep_bias_layer_k<<<9216,256,0,stream>>>(pw, w1, w2, lb, pb,
        glob_b1+(size_t)l*4096, glob_b2+(size_t)l*1024, Gbqkv, Gbqkv+2048, Gbo, Gb1, Gb2);

    gemm_k<0,0,0><<<dim3(24,1),256,0,stream>>>(GN, GWqkv, Gbqkv, nullptr, GQKV, 128, 3072, 1024, 3072);
    attng_k<<<64,256,0,stream>>>(GQKV, GAT);
    gemm_k<0,0,0><<<dim3(8,1),256,0,stream>>>(GAT, GWo, Gbo, nullptr, GO, 128, 1024, 1024, 1024);
    ln_k<3,1><<<128,256,0,stream>>>(GO, G, lw+3*1024, lb+3*1024, G, GN);
    gemm_k<1,0,0><<<dim3(32,1),256,0,stream>>>(GN, GW1, Gb1, nullptr, GFH, 128, 4096, 1024, 4096);
    gemm_k<2,0,0><<<dim3(8,1),256,0,stream>>>(GFH, GW2, Gb2, G, GO, 128, 1024, 4096, 1024);
    ln_k<2,1><<<128,256,0,stream>>>(GO, nullptr, lw+5*1024, lb+5*1024, G, GN);
  }

  tf_k<<<dim3(500,16),256,0,stream>>>(out_w, 32000, out_ln_w, HW, 1024);
  bias_k<<<32000,256,0,stream>>>(out_w, 32000, out_ln_b, out_b, Hb, 1024);
  gemm_k<0,1,0><<<dim3(250,1),256,0,stream>>>(GN, HW, Hb, nullptr, d_out, 128, 32000, 1024, 32000);
}